// Round 8
// baseline (753.517 us; speedup 1.0000x reference)
//
#include <hip/hip_runtime.h>
#include <cmath>

// SimpleHeteroGNN on MI355X — Round 24.
// R23 WIN (560us): LDS-staged Wt fixed sage. Remaining structural waste: each
// layer = agg kernel (writes 25.6MB agg to HBM) + sage kernel (reads it back)
// = ~174MB round-trip + 5 launches + gather latency with nothing to hide it.
// R24: fused gather+MFMA. Gather lane (lm,kq) owns row lm, feat-chunk
// kq*8+ks*32 -> after mean each lane holds the MFMA A-fragments af[ks]
// directly (zero transpose, zero agg buffer). WtS staging/swizzle, fragment
// indices, epilogue all verbatim from R23. Same bytes+VALU per neighbor as
// the old agg (just redistributed); crow index broadcast 16x->4x.

#define NUSR 100000
#define NMOV 20000
#define NEDG 1000000
#define NEUU 500000
#define DH 128

// padded adjacency capacities (degree means 50/10/5; >=6.5 sigma)
#define CAPM 96
#define CAPU 32
#define CAPUU 24

// fine binning geometry
#define NBD 128
#define WD 157            // 128*157 >= 20000; 157*96*4B = 60288B LDS (csr)
#define NBS 128
#define WS 782            // 128*782 >= 100000
#define NBU 196
#define WU 512
#define NBT (NBD + NBS + NBU)  // 452

// per-block LDS staging caps (lambda 8/8/2.6; ~+10 sigma)
#define LCD 36
#define LCS 36
#define LCU 20
// global bucket caps (mean 7812/7812/2551; +7 sigma)
#define BKD 8448
#define BKS 8448
#define BKU 2944

#define NBINB 977         // 977*1024 >= NEDG, 977*512 >= NEUU
#define EPSL 32           // ep slices per bin
#define NEPB (EPSL * 128) // 4096 ep blocks

// block ranges
#define GLU ((NUSR + 127) / 128)        // 782  (lin: 32 rows/wave)
#define GLM ((NMOV + 127) / 128)        // 157
#define GFU 512                         // fused user: 6250 tiles, 2 blocks/CU
#define GFM 313                         // fused movie: 1250 tiles

typedef unsigned short ushort_t;
typedef unsigned char uchar_t;
typedef __attribute__((ext_vector_type(8))) short short8;
typedef __attribute__((ext_vector_type(4))) float f32x4;
typedef __attribute__((ext_vector_type(2))) float f32x2;

__device__ __forceinline__ ushort_t f2bf(float f) {
  unsigned u = __float_as_uint(f);
  u += 0x7FFFu + ((u >> 16) & 1u);
  return (ushort_t)(u >> 16);
}
__device__ __forceinline__ uchar_t f2fp8(float v) {
  return (uchar_t)(__builtin_amdgcn_cvt_pk_fp8_f32(v, v, 0, false) & 0xFF);
}
__device__ __forceinline__ void fp8x8_to_f32(uint2 v, float* f) {
  f32x2 a = __builtin_amdgcn_cvt_pk_f32_fp8((int)v.x, false);
  f32x2 b = __builtin_amdgcn_cvt_pk_f32_fp8((int)v.x, true);
  f32x2 c = __builtin_amdgcn_cvt_pk_f32_fp8((int)v.y, false);
  f32x2 d = __builtin_amdgcn_cvt_pk_f32_fp8((int)v.y, true);
  f[0] = a.x; f[1] = a.y; f[2] = b.x; f[3] = b.y;
  f[4] = c.x; f[5] = c.y; f[6] = d.x; f[7] = d.y;
}
__device__ __forceinline__ int ntl(const int* p) { return __builtin_nontemporal_load(p); }
__device__ __forceinline__ unsigned ntl(const unsigned* p) { return __builtin_nontemporal_load(p); }
__device__ __forceinline__ ushort_t ntl(const ushort_t* p) { return __builtin_nontemporal_load(p); }

// ---------- fused weight prep + BN params + bcnt zero ----------
struct PrepArgs {
  const float* Wl[6];
  const float* Wr[6];
};
__global__ __launch_bounds__(256) void prep_all_k(
    PrepArgs pa, ushort_t* __restrict__ Wt,
    const float* __restrict__ W_user, const float* __restrict__ W_movie,
    ushort_t* __restrict__ WtU, ushort_t* __restrict__ WtM,
    const float* __restrict__ p1b, const float* __restrict__ gamma,
    const float* __restrict__ beta, const float* __restrict__ mean,
    const float* __restrict__ var,
    float* __restrict__ SEP, float* __restrict__ TEP,
    int* __restrict__ bcnt)
{
  int blk = blockIdx.x;
  if (blk < 768) {
    int wi = blk >> 7;
    int idx = (blk & 127) * 256 + threadIdx.x;
    int n = idx >> 8, k = idx & 255;
    const float* Wl = pa.Wl[wi];
    const float* Wr = pa.Wr[wi];
    float v = (k < DH) ? Wl[k * DH + n] : Wr[(k - DH) * DH + n];
    Wt[(size_t)wi * 32768 + n * 256 + k] = f2bf(v);
  } else if (blk < 800) {
    int idx = (blk - 768) * 256 + threadIdx.x;
    int n = idx >> 6, k = idx & 63;
    WtU[n * 64 + k] = f2bf(W_user[k * DH + n]);
  } else if (blk < 864) {
    int idx = (blk - 800) * 256 + threadIdx.x;
    int n = idx >> 7, k = idx & 127;
    WtM[n * 128 + k] = f2bf(W_movie[k * DH + n]);
  } else {
    int f = threadIdx.x;
    if (f < DH) {
      float sc = gamma[f] * rsqrtf(var[f] + 1e-5f);
      SEP[f] = sc;
      TEP[f] = (p1b[f] - mean[f]) * sc + beta[f];
    }
    for (int i = threadIdx.x; i < NBT; i += 256) bcnt[i] = 0;
  }
}

// ---------- phase A1: bin rated edges (d-bins 4B, s-bins 8B with eid) ----------
__global__ __launch_bounds__(256) void bin_rated_k(
    const int* __restrict__ rsrc, const int* __restrict__ rdst,
    unsigned* __restrict__ bkt_d, uint2* __restrict__ bkt_s2,
    int* __restrict__ bcnt)
{
  __shared__ unsigned sb_d[NBD * LCD];
  __shared__ uint2 sb_s[NBS * LCS];
  __shared__ int lcnt[NBD + NBS];
  __shared__ int gbase[NBD + NBS];
  const int tid = threadIdx.x;
  for (int i = tid; i < NBD + NBS; i += 256) lcnt[i] = 0;
  __syncthreads();
  const int c = blockIdx.x;
#pragma unroll
  for (int it = 0; it < 4; ++it) {
    int e = c * 1024 + it * 256 + tid;
    if (e < NEDG) {
      int s = ntl(&rsrc[e]), d = ntl(&rdst[e]);
      int bd = d / WD;
      int o = atomicAdd(&lcnt[bd], 1);
      if (o < LCD) sb_d[bd * LCD + o] = (unsigned)(d - bd * WD) | ((unsigned)s << 8);
      int bs = s / WS;
      int o2 = atomicAdd(&lcnt[NBD + bs], 1);
      if (o2 < LCS)
        sb_s[bs * LCS + o2] =
            make_uint2((unsigned)(s - bs * WS) | ((unsigned)d << 10), (unsigned)e);
    }
  }
  __syncthreads();
  for (int i = tid; i < NBD + NBS; i += 256) {
    int n = lcnt[i];
    if (n > LCD) n = LCD;   // LCD == LCS
    lcnt[i] = n;
    gbase[i] = atomicAdd(&bcnt[i], n);
  }
  __syncthreads();
  const int qw = tid >> 4, lq = tid & 15;
  for (int t = qw; t < NBD + NBS; t += 16) {
    int n = lcnt[t], gb = gbase[t];
    if (t < NBD) {
      if (gb + n > BKD) n = BKD - gb;
      unsigned* gp = bkt_d + (size_t)t * BKD;
      const unsigned* sp = sb_d + t * LCD;
      for (int i = lq; i < n; i += 16) gp[gb + i] = sp[i];
    } else {
      int b = t - NBD;
      if (gb + n > BKS) n = BKS - gb;
      uint2* gp = bkt_s2 + (size_t)b * BKS;
      const uint2* sp = sb_s + b * LCS;
      for (int i = lq; i < n; i += 16) gp[gb + i] = sp[i];
    }
  }
}

// ---------- phase A2: bin uu edges ----------
__global__ __launch_bounds__(256) void bin_uu_k(
    const int* __restrict__ usrc, const int* __restrict__ udst,
    unsigned* __restrict__ bkt_u, int* __restrict__ bcnt)
{
  __shared__ unsigned sb_u[NBU * LCU];
  __shared__ int lcnt[NBU];
  __shared__ int gbase[NBU];
  const int tid = threadIdx.x;
  for (int i = tid; i < NBU; i += 256) lcnt[i] = 0;
  __syncthreads();
  const int c = blockIdx.x;
#pragma unroll
  for (int it = 0; it < 2; ++it) {
    int e = c * 512 + it * 256 + tid;
    if (e < NEUU) {
      int s = ntl(&usrc[e]), d = ntl(&udst[e]);
      int bu = d >> 9;
      int o = atomicAdd(&lcnt[bu], 1);
      if (o < LCU) sb_u[bu * LCU + o] = (unsigned)(d & 511) | ((unsigned)s << 9);
    }
  }
  __syncthreads();
  for (int i = tid; i < NBU; i += 256) {
    int n = lcnt[i];
    if (n > LCU) n = LCU;
    lcnt[i] = n;
    gbase[i] = atomicAdd(&bcnt[NBD + NBS + i], n);
  }
  __syncthreads();
  const int qw = tid >> 4, lq = tid & 15;
  for (int t = qw; t < NBU; t += 16) {
    int n = lcnt[t], gb = gbase[t];
    if (gb + n > BKU) n = BKU - gb;
    unsigned* gp = bkt_u + (size_t)t * BKU;
    const unsigned* sp = sb_u + t * LCU;
    for (int i = lq; i < n; i += 16) gp[gb + i] = sp[i];
  }
}

// ---------- phase B: build CSR slice fully in LDS, flush coalesced ----------
__global__ __launch_bounds__(256) void csr_k(
    const unsigned* __restrict__ bkt_d, const uint2* __restrict__ bkt_s2,
    const unsigned* __restrict__ bkt_u, const int* __restrict__ bcnt,
    int* __restrict__ cnt_m, int* __restrict__ cnt_u, int* __restrict__ cnt_uu,
    int* __restrict__ col_m, ushort_t* __restrict__ col_u, int* __restrict__ col_uu)
{
  __shared__ int lc[WS];                               // 782 ints (max rows/bin)
  __shared__ alignas(16) unsigned cbuf[WD * CAPM];     // 60288B (max slice)
  const int tid = threadIdx.x;
  const int bid = blockIdx.x;
  if (bid < NBD) {
    const int b = bid;
    const int nr = (NMOV - b * WD < WD) ? (NMOV - b * WD) : WD;
    for (int m = tid; m < nr; m += 256) lc[m] = 0;
    __syncthreads();
    int n = bcnt[b]; if (n > BKD) n = BKD;
    const unsigned* B = bkt_d + (size_t)b * BKD;
    for (int i = tid; i < n; i += 256) {
      unsigned v = ntl(&B[i]);
      int m = (int)(v & 255u);
      int o = atomicAdd(&lc[m], 1);
      if (o < CAPM) cbuf[m * CAPM + o] = v >> 8;
    }
    __syncthreads();
    for (int m = tid; m < nr; m += 256) cnt_m[b * WD + m] = lc[m];
    int4* dst = (int4*)(col_m + (size_t)b * WD * CAPM);
    const int4* src = (const int4*)cbuf;
    const int tot = nr * (CAPM / 4);
    for (int i = tid; i < tot; i += 256) dst[i] = src[i];
  } else if (bid < NBD + NBS) {
    const int b = bid - NBD;
    const int nr = (NUSR - b * WS < WS) ? (NUSR - b * WS) : WS;
    for (int u = tid; u < nr; u += 256) lc[u] = 0;
    __syncthreads();
    int n = bcnt[NBD + b]; if (n > BKS) n = BKS;
    const uint2* B = bkt_s2 + (size_t)b * BKS;
    ushort_t* cb16 = (ushort_t*)cbuf;
    for (int i = tid; i < n; i += 256) {
      unsigned v = B[i].x;
      int u = (int)(v & 1023u);
      int o = atomicAdd(&lc[u], 1);
      if (o < CAPU) cb16[u * CAPU + o] = (ushort_t)(v >> 10);
    }
    __syncthreads();
    for (int u = tid; u < nr; u += 256) cnt_u[b * WS + u] = lc[u];
    int4* dst = (int4*)(col_u + (size_t)b * WS * CAPU);
    const int4* src = (const int4*)cbuf;
    const int tot = nr * (CAPU / 8);                   // nr*64B / 16
    for (int i = tid; i < tot; i += 256) dst[i] = src[i];
  } else {
    const int b = bid - NBD - NBS;
    const int nr = (NUSR - b * WU < WU) ? (NUSR - b * WU) : WU;
    for (int u = tid; u < nr; u += 256) lc[u] = 0;
    __syncthreads();
    int n = bcnt[NBD + NBS + b]; if (n > BKU) n = BKU;
    const unsigned* B = bkt_u + (size_t)b * BKU;
    for (int i = tid; i < n; i += 256) {
      unsigned v = ntl(&B[i]);
      int u = (int)(v & 511u);
      int o = atomicAdd(&lc[u], 1);
      if (o < CAPUU) cbuf[u * CAPUU + o] = v >> 9;
    }
    __syncthreads();
    for (int u = tid; u < nr; u += 256) cnt_uu[b * WU + u] = lc[u];
    int4* dst = (int4*)(col_uu + (size_t)b * WU * CAPUU);
    const int4* src = (const int4*)cbuf;
    const int tot = nr * (CAPUU / 4);
    for (int i = tid; i < tot; i += 256) dst[i] = src[i];
  }
}

// ---------- lin GEMM body (fp32 A converted in-register; bf16 + fp8 out) ----------
template <int K>
__device__ __forceinline__ void lin_body(
    int lblk, const float* __restrict__ X, const ushort_t* __restrict__ Wt,
    const float* __restrict__ b, ushort_t* __restrict__ Y,
    uchar_t* __restrict__ Y8, int N)
{
  const int wave = threadIdx.x >> 6;
  const int lane = threadIdx.x & 63;
  const int row0 = (lblk * 4 + wave) * 32;
  if (row0 >= N) return;
  const int lm = lane & 15;
  const int koff = (lane >> 4) * 8;

  f32x4 acc[2][8];
#pragma unroll
  for (int a = 0; a < 2; ++a)
#pragma unroll
    for (int nt = 0; nt < 8; ++nt) acc[a][nt] = (f32x4){0.f, 0.f, 0.f, 0.f};

#pragma unroll
  for (int ks = 0; ks < K / 32; ++ks) {
    short8 af[2];
#pragma unroll
    for (int a = 0; a < 2; ++a) {
      const float* p = X + (size_t)(row0 + a * 16 + lm) * K + ks * 32 + koff;
      float4 v0 = *(const float4*)p;
      float4 v1 = *(const float4*)(p + 4);
      short8 s;
      s[0] = (short)f2bf(v0.x); s[1] = (short)f2bf(v0.y);
      s[2] = (short)f2bf(v0.z); s[3] = (short)f2bf(v0.w);
      s[4] = (short)f2bf(v1.x); s[5] = (short)f2bf(v1.y);
      s[6] = (short)f2bf(v1.z); s[7] = (short)f2bf(v1.w);
      af[a] = s;
    }
#pragma unroll
    for (int nt = 0; nt < 8; ++nt) {
      short8 bf = *(const short8*)&Wt[(nt * 16 + lm) * K + ks * 32 + koff];
      acc[0][nt] = __builtin_amdgcn_mfma_f32_16x16x32_bf16(af[0], bf, acc[0][nt], 0, 0, 0);
      acc[1][nt] = __builtin_amdgcn_mfma_f32_16x16x32_bf16(af[1], bf, acc[1][nt], 0, 0, 0);
    }
  }

  const int quad = lane >> 4;
  float bv[8];
#pragma unroll
  for (int nt = 0; nt < 8; ++nt) bv[nt] = b[nt * 16 + lm];
#pragma unroll
  for (int a = 0; a < 2; ++a) {
#pragma unroll
    for (int reg = 0; reg < 4; ++reg) {
      const int r = row0 + a * 16 + quad * 4 + reg;
      float vv[8];
#pragma unroll
      for (int nt = 0; nt < 8; ++nt)
        vv[nt] = fmaxf(acc[a][nt][reg] + bv[nt], 0.f);
#pragma unroll
      for (int nt = 0; nt < 8; ++nt)
        Y[(size_t)r * DH + nt * 16 + lm] = f2bf(vv[nt]);
#pragma unroll
      for (int nt = 0; nt < 8; ++nt)
        Y8[(size_t)r * DH + nt * 16 + lm] = f2fp8(vv[nt]);
    }
  }
}

// ---------- both input linears in one dispatch ----------
__global__ __launch_bounds__(256) void lin2_k(
    const float* __restrict__ user_feat, const ushort_t* __restrict__ WtU,
    const float* __restrict__ b_user, ushort_t* __restrict__ ux, uchar_t* __restrict__ ux8,
    const float* __restrict__ movie_feat, const ushort_t* __restrict__ WtM,
    const float* __restrict__ b_movie, ushort_t* __restrict__ mx, uchar_t* __restrict__ mx8)
{
  const int blk = blockIdx.x;
  if (blk < GLU) lin_body<64>(blk, user_feat, WtU, b_user, ux, ux8, NUSR);
  else lin_body<128>(blk - GLU, movie_feat, WtM, b_movie, mx, mx8, NMOV);
}

// ---------- fused gather-mean + SAGE MFMA (zero-transpose, no agg buffer) ----------
// Lane (lm,kq) owns row lm of its wave's 16-row tile, feature chunks
// kq*8+ks*32 (ks 0..3). After the mean each lane holds the MFMA A-fragments
// af[ks] directly. Wt staged in LDS (R23 swizzle). A1 = x_dst streamed from
// global for ks 4..7. In-place-safe: wave reads/writes only its own rows.
template <typename CT, int CAP>
__global__ __launch_bounds__(256) void fused_sage_k(
    const uchar_t* __restrict__ x8, const int* __restrict__ cnt,
    const CT* __restrict__ col, const ushort_t* __restrict__ A1,
    const ushort_t* __restrict__ Wt, const float* __restrict__ bl,
    ushort_t* __restrict__ out, uchar_t* __restrict__ out8, int N)
{
  __shared__ alignas(16) ushort_t WtS[32768];   // 64KB
  const int tid = threadIdx.x;
  for (int f = tid; f < 4096; f += 256) {
    const int r = f >> 5, c = f & 31;
    const int4 v = *(const int4*)(Wt + (size_t)f * 8);
    *(int4*)&WtS[(size_t)((r << 5) | (c ^ (r & 31))) << 3] = v;
  }
  __syncthreads();

  const int wave = tid >> 6;
  const int lane = tid & 63;
  const int lm = lane & 15;
  const int kq = lane >> 4;            // 0..3

  float bv[8];
#pragma unroll
  for (int nt = 0; nt < 8; ++nt) bv[nt] = bl[nt * 16 + lm];

  const int T = N >> 4;                // N % 16 == 0 for both node types
  for (int t = (int)blockIdx.x * 4 + wave; t < T; t += (int)gridDim.x * 4) {
    const int row = t * 16 + lm;
    const int deg = cnt[row];
    const int e = (deg < CAP) ? deg : CAP;
    const CT* crow = col + (size_t)row * CAP;
    const uchar_t* xb = x8 + kq * 8;

    float ac[4][8];
#pragma unroll
    for (int ks = 0; ks < 4; ++ks)
#pragma unroll
      for (int j = 0; j < 8; ++j) ac[ks][j] = 0.f;

    int i = 0;
    for (; i + 3 < e; i += 4) {
      int s0 = (int)ntl(&crow[i]);
      int s1 = (int)ntl(&crow[i + 1]);
      int s2 = (int)ntl(&crow[i + 2]);
      int s3 = (int)ntl(&crow[i + 3]);
      uint2 v0[4], v1[4], v2[4], v3[4];
#pragma unroll
      for (int ks = 0; ks < 4; ++ks) {
        v0[ks] = *(const uint2*)(xb + (size_t)s0 * DH + ks * 32);
        v1[ks] = *(const uint2*)(xb + (size_t)s1 * DH + ks * 32);
        v2[ks] = *(const uint2*)(xb + (size_t)s2 * DH + ks * 32);
        v3[ks] = *(const uint2*)(xb + (size_t)s3 * DH + ks * 32);
      }
#pragma unroll
      for (int ks = 0; ks < 4; ++ks) {
        float f0[8], f1[8], f2[8], f3[8];
        fp8x8_to_f32(v0[ks], f0); fp8x8_to_f32(v1[ks], f1);
        fp8x8_to_f32(v2[ks], f2); fp8x8_to_f32(v3[ks], f3);
#pragma unroll
        for (int j = 0; j < 8; ++j)
          ac[ks][j] += (f0[j] + f1[j]) + (f2[j] + f3[j]);
      }
    }
    for (; i < e; ++i) {
      int s = (int)ntl(&crow[i]);
#pragma unroll
      for (int ks = 0; ks < 4; ++ks) {
        uint2 v = *(const uint2*)(xb + (size_t)s * DH + ks * 32);
        float f[8];
        fp8x8_to_f32(v, f);
#pragma unroll
        for (int j = 0; j < 8; ++j) ac[ks][j] += f[j];
      }
    }

    const float inv = 1.f / (float)(deg > 1 ? deg : 1);
    short8 af[4];
#pragma unroll
    for (int ks = 0; ks < 4; ++ks) {
      short8 s;
#pragma unroll
      for (int j = 0; j < 8; ++j) s[j] = (short)f2bf(ac[ks][j] * inv);
      af[ks] = s;
    }

    f32x4 acc[8];
#pragma unroll
    for (int nt = 0; nt < 8; ++nt) acc[nt] = (f32x4){0.f, 0.f, 0.f, 0.f};

#pragma unroll
    for (int ks = 0; ks < 4; ++ks) {
#pragma unroll
      for (int nt = 0; nt < 8; ++nt) {
        const int r = nt * 16 + lm;
        const int c = (ks * 4 + kq) ^ (r & 31);
        short8 bf = *(const short8*)&WtS[(size_t)((r << 5) | c) << 3];
        acc[nt] = __builtin_amdgcn_mfma_f32_16x16x32_bf16(af[ks], bf, acc[nt], 0, 0, 0);
      }
    }
    const ushort_t* a1p = A1 + (size_t)row * DH + kq * 8;
#pragma unroll
    for (int ks = 4; ks < 8; ++ks) {
      short8 afu = *(const short8*)(a1p + (ks - 4) * 32);
#pragma unroll
      for (int nt = 0; nt < 8; ++nt) {
        const int r = nt * 16 + lm;
        const int c = (ks * 4 + kq) ^ (r & 31);
        short8 bf = *(const short8*)&WtS[(size_t)((r << 5) | c) << 3];
        acc[nt] = __builtin_amdgcn_mfma_f32_16x16x32_bf16(afu, bf, acc[nt], 0, 0, 0);
      }
    }

#pragma unroll
    for (int reg = 0; reg < 4; ++reg) {
      const int r = t * 16 + kq * 4 + reg;
      float vv[8];
#pragma unroll
      for (int nt = 0; nt < 8; ++nt)
        vv[nt] = fmaxf(acc[nt][reg] + bv[nt], 0.f);
#pragma unroll
      for (int nt = 0; nt < 8; ++nt)
        out[(size_t)r * DH + nt * 16 + lm] = f2bf(vv[nt]);
      if (out8) {
#pragma unroll
        for (int nt = 0; nt < 8; ++nt)
          out8[(size_t)r * DH + nt * 16 + lm] = f2fp8(vv[nt]);
      }
    }
  }
}

// ---------- fused projection GEMMs: pu = ux@Wu, pm = mx@Wm ----------
__device__ __forceinline__ void proj_body(
    int lblk, const ushort_t* __restrict__ A, const ushort_t* __restrict__ Wt,
    int kofs, ushort_t* __restrict__ out, int N)
{
  const int wave = threadIdx.x >> 6;
  const int lane = threadIdx.x & 63;
  const int row0 = (lblk * 4 + wave) * 32;
  if (row0 >= N) return;
  const int lm = lane & 15;
  const int koff = (lane >> 4) * 8;

  size_t abase[2];
#pragma unroll
  for (int a = 0; a < 2; ++a) abase[a] = (size_t)(row0 + a * 16 + lm) * DH;

  f32x4 acc[2][8];
#pragma unroll
  for (int a = 0; a < 2; ++a)
#pragma unroll
    for (int nt = 0; nt < 8; ++nt) acc[a][nt] = (f32x4){0.f, 0.f, 0.f, 0.f};

#pragma unroll
  for (int ks = 0; ks < 4; ++ks) {
    short8 af[2];
#pragma unroll
    for (int a = 0; a < 2; ++a) af[a] = *(const short8*)(A + abase[a] + ks * 32 + koff);
#pragma unroll
    for (int nt = 0; nt < 8; ++nt) {
      short8 bf = *(const short8*)&Wt[(nt * 16 + lm) * 256 + kofs + ks * 32 + koff];
      acc[0][nt] = __builtin_amdgcn_mfma_f32_16x16x32_bf16(af[0], bf, acc[0][nt], 0, 0, 0);
      acc[1][nt] = __builtin_amdgcn_mfma_f32_16x16x32_bf16(af[1], bf, acc[1][nt], 0, 0, 0);
    }
  }

  const int quad = lane >> 4;
#pragma unroll
  for (int a = 0; a < 2; ++a) {
#pragma unroll
    for (int reg = 0; reg < 4; ++reg) {
      const int r = row0 + a * 16 + quad * 4 + reg;
#pragma unroll
      for (int nt = 0; nt < 8; ++nt)
        out[(size_t)r * DH + nt * 16 + lm] = f2bf(acc[a][nt][reg]);
    }
  }
}

__global__ __launch_bounds__(256) void proj2_k(
    const ushort_t* __restrict__ ux, const ushort_t* __restrict__ mx,
    const ushort_t* __restrict__ Wt, ushort_t* __restrict__ pu,
    ushort_t* __restrict__ pm, int gmU)
{
  if ((int)blockIdx.x < gmU) proj_body(blockIdx.x, ux, Wt, 0, pu, NUSR);
  else proj_body(blockIdx.x - gmU, mx, Wt, DH, pm, NMOV);
}

// ---------- bucket-parallel predictor: 32 slices per user-bin, 2-edge ILP ----------
__global__ __launch_bounds__(256) void ep_bkt_k(
    const ushort_t* __restrict__ pu, const ushort_t* __restrict__ pm,
    const uint2* __restrict__ bkt_s2, const int* __restrict__ bcnt,
    const float* __restrict__ SEP, const float* __restrict__ TEP,
    const float* __restrict__ p2W, const float* __restrict__ p2b,
    float* __restrict__ out)
{
  const int b = (int)blockIdx.x & 127;
  const int sl = (int)blockIdx.x >> 7;     // 0..EPSL-1 (XCD = b%8 for all sl)
  const int tid = threadIdx.x;
  const int lm = tid & 15;
  const int qw = tid >> 4;                 // 0..15
  const int f0 = lm * 8;

  float S[8], T8[8], w2[8];
#pragma unroll
  for (int j = 0; j < 8; ++j) {
    S[j] = SEP[f0 + j];
    T8[j] = TEP[f0 + j];
    w2[j] = p2W[f0 + j];
  }
  const float bias2 = p2b[0];

  int n = bcnt[NBD + b];
  if (n > BKS) n = BKS;
  const uint2* B = bkt_s2 + (size_t)b * BKS;
  const int ub = b * WS;
  const int chunk = (n + EPSL - 1) / EPSL;
  const int st = sl * chunk;
  int en = st + chunk;
  if (en > n) en = n;

  for (int i = st + qw; i < en; i += 32) {
    const int i2 = i + 16;
    const bool v2 = (i2 < en);
    uint2 e0 = B[i];
    uint2 e1 = v2 ? B[i2] : e0;
    int s0 = ub + (int)(e0.x & 1023u), d0 = (int)(e0.x >> 10);
    int s1 = ub + (int)(e1.x & 1023u), d1 = (int)(e1.x >> 10);
    int4 uv0 = *(const int4*)(pu + (s0 << 7) + f0);
    int4 mv0 = *(const int4*)(pm + (d0 << 7) + f0);
    int4 uv1 = *(const int4*)(pu + (s1 << 7) + f0);
    int4 mv1 = *(const int4*)(pm + (d1 << 7) + f0);
    float fu0[8], fm0[8], fu1[8], fm1[8];
    {
      unsigned a0 = (unsigned)uv0.x, b0 = (unsigned)uv0.y, c0 = (unsigned)uv0.z, dd0 = (unsigned)uv0.w;
      fu0[0] = __uint_as_float(a0 << 16); fu0[1] = __uint_as_float(a0 & 0xFFFF0000u);
      fu0[2] = __uint_as_float(b0 << 16); fu0[3] = __uint_as_float(b0 & 0xFFFF0000u);
      fu0[4] = __uint_as_float(c0 << 16); fu0[5] = __uint_as_float(c0 & 0xFFFF0000u);
      fu0[6] = __uint_as_float(dd0 << 16); fu0[7] = __uint_as_float(dd0 & 0xFFFF0000u);
      unsigned a1 = (unsigned)mv0.x, b1 = (unsigned)mv0.y, c1 = (unsigned)mv0.z, dd1 = (unsigned)mv0.w;
      fm0[0] = __uint_as_float(a1 << 16); fm0[1] = __uint_as_float(a1 & 0xFFFF0000u);
      fm0[2] = __uint_as_float(b1 << 16); fm0[3] = __uint_as_float(b1 & 0xFFFF0000u);
      fm0[4] = __uint_as_float(c1 << 16); fm0[5] = __uint_as_float(c1 & 0xFFFF0000u);
      fm0[6] = __uint_as_float(dd1 << 16); fm0[7] = __uint_as_float(dd1 & 0xFFFF0000u);
      unsigned a2 = (unsigned)uv1.x, b2 = (unsigned)uv1.y, c2 = (unsigned)uv1.z, dd2 = (unsigned)uv1.w;
      fu1[0] = __uint_as_float(a2 << 16); fu1[1] = __uint_as_float(a2 & 0xFFFF0000u);
      fu1[2] = __uint_as_float(b2 << 16); fu1[3] = __uint_as_float(b2 & 0xFFFF0000u);
      fu1[4] = __uint_as_float(c2 << 16); fu1[5] = __uint_as_float(c2 & 0xFFFF0000u);
      fu1[6] = __uint_as_float(dd2 << 16); fu1[7] = __uint_as_float(dd2 & 0xFFFF0000u);
      unsigned a3 = (unsigned)mv1.x, b3 = (unsigned)mv1.y, c3 = (unsigned)mv1.z, dd3 = (unsigned)mv1.w;
      fm1[0] = __uint_as_float(a3 << 16); fm1[1] = __uint_as_float(a3 & 0xFFFF0000u);
      fm1[2] = __uint_as_float(b3 << 16); fm1[3] = __uint_as_float(b3 & 0xFFFF0000u);
      fm1[4] = __uint_as_float(c3 << 16); fm1[5] = __uint_as_float(c3 & 0xFFFF0000u);
      fm1[6] = __uint_as_float(dd3 << 16); fm1[7] = __uint_as_float(dd3 & 0xFFFF0000u);
    }
    float p0 = 0.f, p1 = 0.f;
#pragma unroll
    for (int j = 0; j < 8; ++j) {
      float h0 = fmaxf(fmaf(fu0[j] + fm0[j], S[j], T8[j]), 0.f);
      p0 = fmaf(h0, w2[j], p0);
      float h1 = fmaxf(fmaf(fu1[j] + fm1[j], S[j], T8[j]), 0.f);
      p1 = fmaf(h1, w2[j], p1);
    }
    p0 += __shfl_xor(p0, 1, 16);
    p0 += __shfl_xor(p0, 2, 16);
    p0 += __shfl_xor(p0, 4, 16);
    p0 += __shfl_xor(p0, 8, 16);
    p1 += __shfl_xor(p1, 1, 16);
    p1 += __shfl_xor(p1, 2, 16);
    p1 += __shfl_xor(p1, 4, 16);
    p1 += __shfl_xor(p1, 8, 16);
    if (lm == 0) {
      __builtin_nontemporal_store(4.f / (1.f + expf(-(p0 + bias2))) + 1.f, &out[e0.y]);
      if (v2)
        __builtin_nontemporal_store(4.f / (1.f + expf(-(p1 + bias2))) + 1.f, &out[e1.y]);
    }
  }
}

extern "C" void kernel_launch(void* const* d_in, const int* in_sizes, int n_in,
                              void* d_out, int out_size, void* d_ws, size_t ws_size,
                              hipStream_t stream)
{
  const float* user_feat = (const float*)d_in[0];
  const float* movie_feat = (const float*)d_in[1];
  const float* W_user = (const float*)d_in[2];
  const float* b_user = (const float*)d_in[3];
  const float* W_movie = (const float*)d_in[4];
  const float* b_movie = (const float*)d_in[5];
  const float* u2m1_Wl = (const float*)d_in[6];
  const float* u2m1_bl = (const float*)d_in[7];
  const float* u2m1_Wr = (const float*)d_in[8];
  const float* m2u1_Wl = (const float*)d_in[9];
  const float* m2u1_bl = (const float*)d_in[10];
  const float* m2u1_Wr = (const float*)d_in[11];
  const float* u2m2_Wl = (const float*)d_in[12];
  const float* u2m2_bl = (const float*)d_in[13];
  const float* u2m2_Wr = (const float*)d_in[14];
  const float* m2u2_Wl = (const float*)d_in[15];
  const float* m2u2_bl = (const float*)d_in[16];
  const float* m2u2_Wr = (const float*)d_in[17];
  const float* u2u_Wl = (const float*)d_in[18];
  const float* u2u_bl = (const float*)d_in[19];
  const float* u2u_Wr = (const float*)d_in[20];
  const float* p1_W = (const float*)d_in[21];
  const float* p1_b = (const float*)d_in[22];
  const float* bn_gamma = (const float*)d_in[23];
  const float* bn_beta = (const float*)d_in[24];
  const float* bn_mean = (const float*)d_in[25];
  const float* bn_var = (const float*)d_in[26];
  const float* p2_W = (const float*)d_in[27];
  const float* p2_b = (const float*)d_in[28];
  const int* rated_src = (const int*)d_in[29];
  const int* rated_dst = (const int*)d_in[30];
  const int* uu_src = (const int*)d_in[31];
  const int* uu_dst = (const int*)d_in[32];

  // ---- workspace layout (~110.5 MB; known-good footprint is 113 MB) ----
  ushort_t* ux = (ushort_t*)d_ws;                       // NU*128 bf16
  ushort_t* mx = ux + (size_t)NUSR * DH;                // NM*128
  ushort_t* agg = mx + (size_t)NMOV * DH;               // NU*128 (pu; bkt_d/bkt_u alias pre-fill)
  ushort_t* pm = agg + (size_t)NUSR * DH;               // NM*128
  ushort_t* Wt = pm + (size_t)NMOV * DH;                // 6 * 32768
  ushort_t* WtU = Wt + 6 * 32768;                       // 128*64
  ushort_t* WtM = WtU + 8192;                           // 128*128
  float* SEP = (float*)(WtM + 16384);                   // 128
  float* TEP = SEP + DH;                                // 128
  int* col_m = (int*)(TEP + DH);                        // NMOV*CAPM ints
  ushort_t* col_u = (ushort_t*)(col_m + (size_t)NMOV * CAPM);   // NUSR*CAPU ushorts
  int* col_uu = (int*)(col_u + (size_t)NUSR * CAPU);    // NUSR*CAPUU ints
  int* cntbuf = col_uu + (size_t)NUSR * CAPUU;          // NMOV+2*NUSR+NBT
  uchar_t* ux8 = (uchar_t*)(cntbuf + (NMOV + 2 * NUSR + NBT));  // NU*128 fp8
  uchar_t* mx8 = ux8 + (size_t)NUSR * DH;               // NM*128 fp8
  uint2* bkt_s2 = (uint2*)(mx8 + (size_t)NMOV * DH);    // 128*BKS uint2 (8.65MB, survives to ep)
  int* cnt_m = cntbuf;
  int* cnt_u = cntbuf + NMOV;
  int* cnt_uu = cntbuf + NMOV + NUSR;
  int* bcnt = cntbuf + NMOV + 2 * NUSR;                 // NBT bucket cursors

  // d/u edge buckets alias agg (6.6MB < 25.6MB; both drained by csr_k which
  // runs before proj2_k writes pu=agg; fused layers never touch agg)
  unsigned* bkt_d = (unsigned*)agg;
  unsigned* bkt_u = bkt_d + (size_t)NBD * BKD;

  ushort_t* Wt_u2m1 = Wt + 0 * 32768;
  ushort_t* Wt_m2u1 = Wt + 1 * 32768;
  ushort_t* Wt_u2m2 = Wt + 2 * 32768;
  ushort_t* Wt_m2u2 = Wt + 3 * 32768;
  ushort_t* Wt_u2u  = Wt + 4 * 32768;
  ushort_t* Wt_p1   = Wt + 5 * 32768;
  ushort_t* pu = agg;

  // ---- fused weight prep + BN params + bcnt zero ----
  PrepArgs pa;
  pa.Wl[0] = u2m1_Wl; pa.Wr[0] = u2m1_Wr;
  pa.Wl[1] = m2u1_Wl; pa.Wr[1] = m2u1_Wr;
  pa.Wl[2] = u2m2_Wl; pa.Wr[2] = u2m2_Wr;
  pa.Wl[3] = m2u2_Wl; pa.Wr[3] = m2u2_Wr;
  pa.Wl[4] = u2u_Wl;  pa.Wr[4] = u2u_Wr;
  pa.Wl[5] = p1_W;    pa.Wr[5] = p1_W + DH * DH;
  prep_all_k<<<865, 256, 0, stream>>>(
      pa, Wt, W_user, W_movie, WtU, WtM,
      p1_b, bn_gamma, bn_beta, bn_mean, bn_var, SEP, TEP, bcnt);

  // ---- two-phase fill (fine bins -> LDS CSR assembly), then input linears ----
  bin_rated_k<<<NBINB, 256, 0, stream>>>(
      rated_src, rated_dst, bkt_d, bkt_s2, bcnt);
  bin_uu_k<<<NBINB, 256, 0, stream>>>(uu_src, uu_dst, bkt_u, bcnt);
  csr_k<<<NBT, 256, 0, stream>>>(
      bkt_d, bkt_s2, bkt_u, bcnt, cnt_m, cnt_u, cnt_uu, col_m, col_u, col_uu);
  lin2_k<<<GLU + GLM, 256, 0, stream>>>(
      user_feat, WtU, b_user, ux, ux8, movie_feat, WtM, b_movie, mx, mx8);

  // ---- 5 fused SAGE layers (gather-mean + MFMA in one kernel) ----
  // u2m1: gather ux8; A1 = mx; update mx (+mx8)
  fused_sage_k<int, CAPM><<<GFM, 256, 0, stream>>>(
      ux8, cnt_m, col_m, mx, Wt_u2m1, u2m1_bl, mx, mx8, NMOV);
  // m2u1: gather mx8; A1 = ux; update ux (+ux8)
  fused_sage_k<ushort_t, CAPU><<<GFU, 256, 0, stream>>>(
      mx8, cnt_u, col_u, ux, Wt_m2u1, m2u1_bl, ux, ux8, NUSR);
  // u2m2
  fused_sage_k<int, CAPM><<<GFM, 256, 0, stream>>>(
      ux8, cnt_m, col_m, mx, Wt_u2m2, u2m2_bl, mx, mx8, NMOV);
  // m2u2
  fused_sage_k<ushort_t, CAPU><<<GFU, 256, 0, stream>>>(
      mx8, cnt_u, col_u, ux, Wt_m2u2, m2u2_bl, ux, ux8, NUSR);
  // u2u: final user layer; no fp8 copy needed afterwards
  fused_sage_k<int, CAPUU><<<GFU, 256, 0, stream>>>(
      ux8, cnt_uu, col_uu, ux, Wt_u2u, u2u_bl, ux, (uchar_t*)nullptr, NUSR);

  // ---- factored edge MLP (bf16 throughout; bucket-ordered predictor) ----
  const int gmU = (NUSR + 127) / 128, gmM = (NMOV + 127) / 128;
  proj2_k<<<gmU + gmM, 256, 0, stream>>>(ux, mx, Wt_p1, pu, pm, gmU);
  ep_bkt_k<<<NEPB, 256, 0, stream>>>(
      pu, pm, bkt_s2, bcnt, SEP, TEP, p2_W, p2_b, (float*)d_out);
}

// Round 9
// 691.445 us; speedup vs baseline: 1.0898x; 1.0898x over previous
//
#include <hip/hip_runtime.h>
#include <cmath>

// SimpleHeteroGNN on MI355X — Round 25.
// R24 post-mortem: fused gather+MFMA = 95us @ 9% occupancy (188 VGPR + 64KB
// LDS killed residency; gather latency fully exposed). REVERT to R23 (560us).
// New change, ep only: pm[d] random reads miss L2 (5.1MB vs 4MB/XCD; ~103MB
// of ep's 137MB FETCH). Iterate each slice chunk in 10 movie-subbin passes
// (d>>11 == sb): pm slice 512KB/pass stays L2-resident; pu slices (3.2MB/XCD)
// stay resident across passes; skipped entries are L1 hits. Subbin test is
// quarter-wave-uniform. Same math, same out[eid]; only visit order changes.

#define NUSR 100000
#define NMOV 20000
#define NEDG 1000000
#define NEUU 500000
#define DH 128

// padded adjacency capacities (degree means 50/10/5; >=6.5 sigma)
#define CAPM 96
#define CAPU 32
#define CAPUU 24

// fine binning geometry
#define NBD 128
#define WD 157            // 128*157 >= 20000; 157*96*4B = 60288B LDS (csr)
#define NBS 128
#define WS 782            // 128*782 >= 100000
#define NBU 196
#define WU 512
#define NBT (NBD + NBS + NBU)  // 452

// per-block LDS staging caps (lambda 8/8/2.6; ~+10 sigma)
#define LCD 36
#define LCS 36
#define LCU 20
// global bucket caps (mean 7812/7812/2551; +7 sigma)
#define BKD 8448
#define BKS 8448
#define BKU 2944

#define NBINB 977         // 977*1024 >= NEDG, 977*512 >= NEUU
#define EPSL 32           // ep slices per bin
#define NEPB (EPSL * 128) // 4096 ep blocks
#define NSB 10            // movie subbins (d>>11), 512KB pm slice each

// block ranges
#define GLU ((NUSR + 127) / 128)        // 782  (lin: 32 rows/wave)
#define GLM ((NMOV + 127) / 128)        // 157
#define GSU 512                         // sage user: 3125 tiles, 2 blocks/CU
#define GSM 157                         // sage movie: 625 tiles

typedef unsigned short ushort_t;
typedef unsigned char uchar_t;
typedef __attribute__((ext_vector_type(8))) short short8;
typedef __attribute__((ext_vector_type(4))) float f32x4;
typedef __attribute__((ext_vector_type(2))) float f32x2;

__device__ __forceinline__ ushort_t f2bf(float f) {
  unsigned u = __float_as_uint(f);
  u += 0x7FFFu + ((u >> 16) & 1u);
  return (ushort_t)(u >> 16);
}
__device__ __forceinline__ uchar_t f2fp8(float v) {
  return (uchar_t)(__builtin_amdgcn_cvt_pk_fp8_f32(v, v, 0, false) & 0xFF);
}
__device__ __forceinline__ void fp8x8_to_f32(uint2 v, float* f) {
  f32x2 a = __builtin_amdgcn_cvt_pk_f32_fp8((int)v.x, false);
  f32x2 b = __builtin_amdgcn_cvt_pk_f32_fp8((int)v.x, true);
  f32x2 c = __builtin_amdgcn_cvt_pk_f32_fp8((int)v.y, false);
  f32x2 d = __builtin_amdgcn_cvt_pk_f32_fp8((int)v.y, true);
  f[0] = a.x; f[1] = a.y; f[2] = b.x; f[3] = b.y;
  f[4] = c.x; f[5] = c.y; f[6] = d.x; f[7] = d.y;
}
__device__ __forceinline__ int ntl(const int* p) { return __builtin_nontemporal_load(p); }
__device__ __forceinline__ unsigned ntl(const unsigned* p) { return __builtin_nontemporal_load(p); }
__device__ __forceinline__ ushort_t ntl(const ushort_t* p) { return __builtin_nontemporal_load(p); }

// ---------- fused weight prep + BN params + bcnt zero ----------
struct PrepArgs {
  const float* Wl[6];
  const float* Wr[6];
};
__global__ __launch_bounds__(256) void prep_all_k(
    PrepArgs pa, ushort_t* __restrict__ Wt,
    const float* __restrict__ W_user, const float* __restrict__ W_movie,
    ushort_t* __restrict__ WtU, ushort_t* __restrict__ WtM,
    const float* __restrict__ p1b, const float* __restrict__ gamma,
    const float* __restrict__ beta, const float* __restrict__ mean,
    const float* __restrict__ var,
    float* __restrict__ SEP, float* __restrict__ TEP,
    int* __restrict__ bcnt)
{
  int blk = blockIdx.x;
  if (blk < 768) {
    int wi = blk >> 7;
    int idx = (blk & 127) * 256 + threadIdx.x;
    int n = idx >> 8, k = idx & 255;
    const float* Wl = pa.Wl[wi];
    const float* Wr = pa.Wr[wi];
    float v = (k < DH) ? Wl[k * DH + n] : Wr[(k - DH) * DH + n];
    Wt[(size_t)wi * 32768 + n * 256 + k] = f2bf(v);
  } else if (blk < 800) {
    int idx = (blk - 768) * 256 + threadIdx.x;
    int n = idx >> 6, k = idx & 63;
    WtU[n * 64 + k] = f2bf(W_user[k * DH + n]);
  } else if (blk < 864) {
    int idx = (blk - 800) * 256 + threadIdx.x;
    int n = idx >> 7, k = idx & 127;
    WtM[n * 128 + k] = f2bf(W_movie[k * DH + n]);
  } else {
    int f = threadIdx.x;
    if (f < DH) {
      float sc = gamma[f] * rsqrtf(var[f] + 1e-5f);
      SEP[f] = sc;
      TEP[f] = (p1b[f] - mean[f]) * sc + beta[f];
    }
    for (int i = threadIdx.x; i < NBT; i += 256) bcnt[i] = 0;
  }
}

// ---------- phase A1: bin rated edges (d-bins 4B, s-bins 8B with eid) ----------
__global__ __launch_bounds__(256) void bin_rated_k(
    const int* __restrict__ rsrc, const int* __restrict__ rdst,
    unsigned* __restrict__ bkt_d, uint2* __restrict__ bkt_s2,
    int* __restrict__ bcnt)
{
  __shared__ unsigned sb_d[NBD * LCD];
  __shared__ uint2 sb_s[NBS * LCS];
  __shared__ int lcnt[NBD + NBS];
  __shared__ int gbase[NBD + NBS];
  const int tid = threadIdx.x;
  for (int i = tid; i < NBD + NBS; i += 256) lcnt[i] = 0;
  __syncthreads();
  const int c = blockIdx.x;
#pragma unroll
  for (int it = 0; it < 4; ++it) {
    int e = c * 1024 + it * 256 + tid;
    if (e < NEDG) {
      int s = ntl(&rsrc[e]), d = ntl(&rdst[e]);
      int bd = d / WD;
      int o = atomicAdd(&lcnt[bd], 1);
      if (o < LCD) sb_d[bd * LCD + o] = (unsigned)(d - bd * WD) | ((unsigned)s << 8);
      int bs = s / WS;
      int o2 = atomicAdd(&lcnt[NBD + bs], 1);
      if (o2 < LCS)
        sb_s[bs * LCS + o2] =
            make_uint2((unsigned)(s - bs * WS) | ((unsigned)d << 10), (unsigned)e);
    }
  }
  __syncthreads();
  for (int i = tid; i < NBD + NBS; i += 256) {
    int n = lcnt[i];
    if (n > LCD) n = LCD;   // LCD == LCS
    lcnt[i] = n;
    gbase[i] = atomicAdd(&bcnt[i], n);
  }
  __syncthreads();
  const int qw = tid >> 4, lq = tid & 15;
  for (int t = qw; t < NBD + NBS; t += 16) {
    int n = lcnt[t], gb = gbase[t];
    if (t < NBD) {
      if (gb + n > BKD) n = BKD - gb;
      unsigned* gp = bkt_d + (size_t)t * BKD;
      const unsigned* sp = sb_d + t * LCD;
      for (int i = lq; i < n; i += 16) gp[gb + i] = sp[i];
    } else {
      int b = t - NBD;
      if (gb + n > BKS) n = BKS - gb;
      uint2* gp = bkt_s2 + (size_t)b * BKS;
      const uint2* sp = sb_s + b * LCS;
      for (int i = lq; i < n; i += 16) gp[gb + i] = sp[i];
    }
  }
}

// ---------- phase A2: bin uu edges ----------
__global__ __launch_bounds__(256) void bin_uu_k(
    const int* __restrict__ usrc, const int* __restrict__ udst,
    unsigned* __restrict__ bkt_u, int* __restrict__ bcnt)
{
  __shared__ unsigned sb_u[NBU * LCU];
  __shared__ int lcnt[NBU];
  __shared__ int gbase[NBU];
  const int tid = threadIdx.x;
  for (int i = tid; i < NBU; i += 256) lcnt[i] = 0;
  __syncthreads();
  const int c = blockIdx.x;
#pragma unroll
  for (int it = 0; it < 2; ++it) {
    int e = c * 512 + it * 256 + tid;
    if (e < NEUU) {
      int s = ntl(&usrc[e]), d = ntl(&udst[e]);
      int bu = d >> 9;
      int o = atomicAdd(&lcnt[bu], 1);
      if (o < LCU) sb_u[bu * LCU + o] = (unsigned)(d & 511) | ((unsigned)s << 9);
    }
  }
  __syncthreads();
  for (int i = tid; i < NBU; i += 256) {
    int n = lcnt[i];
    if (n > LCU) n = LCU;
    lcnt[i] = n;
    gbase[i] = atomicAdd(&bcnt[NBD + NBS + i], n);
  }
  __syncthreads();
  const int qw = tid >> 4, lq = tid & 15;
  for (int t = qw; t < NBU; t += 16) {
    int n = lcnt[t], gb = gbase[t];
    if (gb + n > BKU) n = BKU - gb;
    unsigned* gp = bkt_u + (size_t)t * BKU;
    const unsigned* sp = sb_u + t * LCU;
    for (int i = lq; i < n; i += 16) gp[gb + i] = sp[i];
  }
}

// ---------- phase B: build CSR slice fully in LDS, flush coalesced ----------
__global__ __launch_bounds__(256) void csr_k(
    const unsigned* __restrict__ bkt_d, const uint2* __restrict__ bkt_s2,
    const unsigned* __restrict__ bkt_u, const int* __restrict__ bcnt,
    int* __restrict__ cnt_m, int* __restrict__ cnt_u, int* __restrict__ cnt_uu,
    int* __restrict__ col_m, ushort_t* __restrict__ col_u, int* __restrict__ col_uu)
{
  __shared__ int lc[WS];                               // 782 ints (max rows/bin)
  __shared__ alignas(16) unsigned cbuf[WD * CAPM];     // 60288B (max slice)
  const int tid = threadIdx.x;
  const int bid = blockIdx.x;
  if (bid < NBD) {
    const int b = bid;
    const int nr = (NMOV - b * WD < WD) ? (NMOV - b * WD) : WD;
    for (int m = tid; m < nr; m += 256) lc[m] = 0;
    __syncthreads();
    int n = bcnt[b]; if (n > BKD) n = BKD;
    const unsigned* B = bkt_d + (size_t)b * BKD;
    for (int i = tid; i < n; i += 256) {
      unsigned v = ntl(&B[i]);
      int m = (int)(v & 255u);
      int o = atomicAdd(&lc[m], 1);
      if (o < CAPM) cbuf[m * CAPM + o] = v >> 8;
    }
    __syncthreads();
    for (int m = tid; m < nr; m += 256) cnt_m[b * WD + m] = lc[m];
    int4* dst = (int4*)(col_m + (size_t)b * WD * CAPM);
    const int4* src = (const int4*)cbuf;
    const int tot = nr * (CAPM / 4);
    for (int i = tid; i < tot; i += 256) dst[i] = src[i];
  } else if (bid < NBD + NBS) {
    const int b = bid - NBD;
    const int nr = (NUSR - b * WS < WS) ? (NUSR - b * WS) : WS;
    for (int u = tid; u < nr; u += 256) lc[u] = 0;
    __syncthreads();
    int n = bcnt[NBD + b]; if (n > BKS) n = BKS;
    const uint2* B = bkt_s2 + (size_t)b * BKS;
    ushort_t* cb16 = (ushort_t*)cbuf;
    for (int i = tid; i < n; i += 256) {
      unsigned v = B[i].x;
      int u = (int)(v & 1023u);
      int o = atomicAdd(&lc[u], 1);
      if (o < CAPU) cb16[u * CAPU + o] = (ushort_t)(v >> 10);
    }
    __syncthreads();
    for (int u = tid; u < nr; u += 256) cnt_u[b * WS + u] = lc[u];
    int4* dst = (int4*)(col_u + (size_t)b * WS * CAPU);
    const int4* src = (const int4*)cbuf;
    const int tot = nr * (CAPU / 8);                   // nr*64B / 16
    for (int i = tid; i < tot; i += 256) dst[i] = src[i];
  } else {
    const int b = bid - NBD - NBS;
    const int nr = (NUSR - b * WU < WU) ? (NUSR - b * WU) : WU;
    for (int u = tid; u < nr; u += 256) lc[u] = 0;
    __syncthreads();
    int n = bcnt[NBD + NBS + b]; if (n > BKU) n = BKU;
    const unsigned* B = bkt_u + (size_t)b * BKU;
    for (int i = tid; i < n; i += 256) {
      unsigned v = ntl(&B[i]);
      int u = (int)(v & 511u);
      int o = atomicAdd(&lc[u], 1);
      if (o < CAPUU) cbuf[u * CAPUU + o] = v >> 9;
    }
    __syncthreads();
    for (int u = tid; u < nr; u += 256) cnt_uu[b * WU + u] = lc[u];
    int4* dst = (int4*)(col_uu + (size_t)b * WU * CAPUU);
    const int4* src = (const int4*)cbuf;
    const int tot = nr * (CAPUU / 4);
    for (int i = tid; i < tot; i += 256) dst[i] = src[i];
  }
}

// ---------- lin GEMM body (fp32 A converted in-register; bf16 + fp8 out) ----------
template <int K>
__device__ __forceinline__ void lin_body(
    int lblk, const float* __restrict__ X, const ushort_t* __restrict__ Wt,
    const float* __restrict__ b, ushort_t* __restrict__ Y,
    uchar_t* __restrict__ Y8, int N)
{
  const int wave = threadIdx.x >> 6;
  const int lane = threadIdx.x & 63;
  const int row0 = (lblk * 4 + wave) * 32;
  if (row0 >= N) return;
  const int lm = lane & 15;
  const int koff = (lane >> 4) * 8;

  f32x4 acc[2][8];
#pragma unroll
  for (int a = 0; a < 2; ++a)
#pragma unroll
    for (int nt = 0; nt < 8; ++nt) acc[a][nt] = (f32x4){0.f, 0.f, 0.f, 0.f};

#pragma unroll
  for (int ks = 0; ks < K / 32; ++ks) {
    short8 af[2];
#pragma unroll
    for (int a = 0; a < 2; ++a) {
      const float* p = X + (size_t)(row0 + a * 16 + lm) * K + ks * 32 + koff;
      float4 v0 = *(const float4*)p;
      float4 v1 = *(const float4*)(p + 4);
      short8 s;
      s[0] = (short)f2bf(v0.x); s[1] = (short)f2bf(v0.y);
      s[2] = (short)f2bf(v0.z); s[3] = (short)f2bf(v0.w);
      s[4] = (short)f2bf(v1.x); s[5] = (short)f2bf(v1.y);
      s[6] = (short)f2bf(v1.z); s[7] = (short)f2bf(v1.w);
      af[a] = s;
    }
#pragma unroll
    for (int nt = 0; nt < 8; ++nt) {
      short8 bf = *(const short8*)&Wt[(nt * 16 + lm) * K + ks * 32 + koff];
      acc[0][nt] = __builtin_amdgcn_mfma_f32_16x16x32_bf16(af[0], bf, acc[0][nt], 0, 0, 0);
      acc[1][nt] = __builtin_amdgcn_mfma_f32_16x16x32_bf16(af[1], bf, acc[1][nt], 0, 0, 0);
    }
  }

  const int quad = lane >> 4;
  float bv[8];
#pragma unroll
  for (int nt = 0; nt < 8; ++nt) bv[nt] = b[nt * 16 + lm];
#pragma unroll
  for (int a = 0; a < 2; ++a) {
#pragma unroll
    for (int reg = 0; reg < 4; ++reg) {
      const int r = row0 + a * 16 + quad * 4 + reg;
      float vv[8];
#pragma unroll
      for (int nt = 0; nt < 8; ++nt)
        vv[nt] = fmaxf(acc[a][nt][reg] + bv[nt], 0.f);
#pragma unroll
      for (int nt = 0; nt < 8; ++nt)
        Y[(size_t)r * DH + nt * 16 + lm] = f2bf(vv[nt]);
#pragma unroll
      for (int nt = 0; nt < 8; ++nt)
        Y8[(size_t)r * DH + nt * 16 + lm] = f2fp8(vv[nt]);
    }
  }
}

// ---------- both input linears in one dispatch ----------
__global__ __launch_bounds__(256) void lin2_k(
    const float* __restrict__ user_feat, const ushort_t* __restrict__ WtU,
    const float* __restrict__ b_user, ushort_t* __restrict__ ux, uchar_t* __restrict__ ux8,
    const float* __restrict__ movie_feat, const ushort_t* __restrict__ WtM,
    const float* __restrict__ b_movie, ushort_t* __restrict__ mx, uchar_t* __restrict__ mx8)
{
  const int blk = blockIdx.x;
  if (blk < GLU) lin_body<64>(blk, user_feat, WtU, b_user, ux, ux8, NUSR);
  else lin_body<128>(blk - GLU, movie_feat, WtM, b_movie, mx, mx8, NMOV);
}

// ---------- gather-mean over padded adjacency, fp8 source: 4 rows/wave ----------
template <typename CT, int CAP, int UNR>
__global__ __launch_bounds__(256) void agg_mean4_k(
    const uchar_t* __restrict__ x8, const int* __restrict__ cnt,
    const CT* __restrict__ col, ushort_t* __restrict__ out, int N)
{
  const int wave = threadIdx.x >> 6;
  const int lane = threadIdx.x & 63;
  const int lm = lane & 15, q = lane >> 4;
  const int row = blockIdx.x * 16 + wave * 4 + q;
  if (row >= N) return;
  const int deg = cnt[row];
  const int e = (deg < CAP) ? deg : CAP;
  const CT* crow = col + (size_t)row * CAP;
  float a[8];
#pragma unroll
  for (int j = 0; j < 8; ++j) a[j] = 0.f;
  int i = 0;
  if (UNR >= 16) {
    for (; i + 15 < e; i += 16) {
      uint2 v[16];
#pragma unroll
      for (int u = 0; u < 16; ++u) {
        int s = (int)ntl(&crow[i + u]);
        v[u] = *(const uint2*)(x8 + (size_t)s * DH + lm * 8);
      }
#pragma unroll
      for (int u = 0; u < 16; ++u) {
        float f0[8];
        fp8x8_to_f32(v[u], f0);
#pragma unroll
        for (int j = 0; j < 8; ++j) a[j] += f0[j];
      }
    }
  }
  if (UNR >= 8) {
    for (; i + 7 < e; i += 8) {
      uint2 v[8];
#pragma unroll
      for (int u = 0; u < 8; ++u) {
        int s = (int)ntl(&crow[i + u]);
        v[u] = *(const uint2*)(x8 + (size_t)s * DH + lm * 8);
      }
#pragma unroll
      for (int u = 0; u < 8; ++u) {
        float f0[8];
        fp8x8_to_f32(v[u], f0);
#pragma unroll
        for (int j = 0; j < 8; ++j) a[j] += f0[j];
      }
    }
  }
  for (; i + 3 < e; i += 4) {
    uint2 v0, v1, v2, v3;
    int s0 = (int)ntl(&crow[i]), s1 = (int)ntl(&crow[i + 1]);
    int s2 = (int)ntl(&crow[i + 2]), s3 = (int)ntl(&crow[i + 3]);
    v0 = *(const uint2*)(x8 + (size_t)s0 * DH + lm * 8);
    v1 = *(const uint2*)(x8 + (size_t)s1 * DH + lm * 8);
    v2 = *(const uint2*)(x8 + (size_t)s2 * DH + lm * 8);
    v3 = *(const uint2*)(x8 + (size_t)s3 * DH + lm * 8);
    float f0[8], f1[8], f2[8], f3[8];
    fp8x8_to_f32(v0, f0); fp8x8_to_f32(v1, f1);
    fp8x8_to_f32(v2, f2); fp8x8_to_f32(v3, f3);
#pragma unroll
    for (int j = 0; j < 8; ++j) a[j] += (f0[j] + f1[j]) + (f2[j] + f3[j]);
  }
  for (; i < e; ++i) {
    uint2 v0 = *(const uint2*)(x8 + (size_t)(int)ntl(&crow[i]) * DH + lm * 8);
    float f0[8];
    fp8x8_to_f32(v0, f0);
#pragma unroll
    for (int j = 0; j < 8; ++j) a[j] += f0[j];
  }
  float inv = 1.f / (float)(deg > 1 ? deg : 1);
  unsigned p0 = f2bf(a[0] * inv) | ((unsigned)f2bf(a[1] * inv) << 16);
  unsigned p1 = f2bf(a[2] * inv) | ((unsigned)f2bf(a[3] * inv) << 16);
  unsigned p2 = f2bf(a[4] * inv) | ((unsigned)f2bf(a[5] * inv) << 16);
  unsigned p3 = f2bf(a[6] * inv) | ((unsigned)f2bf(a[7] * inv) << 16);
  *(int4*)(out + (size_t)row * DH + lm * 8) = make_int4(p0, p1, p2, p3);
}

// ---------- SAGE update GEMM: Wt staged in LDS (swizzled), grid-strided ----------
// Wt viewed as 128 rows x 32 chunks of 16B; chunk (r,c) stored at (r, c^(r&31)).
// Inner loop: 64 conflict-free ds_read_b128 + 128 MFMA per 32-row tile.
__global__ __launch_bounds__(256) void sage_mfma_k(
    const ushort_t* __restrict__ A0, const ushort_t* __restrict__ A1,
    const ushort_t* __restrict__ Wt, const float* __restrict__ bl,
    ushort_t* __restrict__ out, uchar_t* __restrict__ out8, int N)
{
  __shared__ alignas(16) ushort_t WtS[32768];   // 64KB
  const int tid = threadIdx.x;
  for (int f = tid; f < 4096; f += 256) {
    const int r = f >> 5, c = f & 31;
    const int4 v = *(const int4*)(Wt + (size_t)f * 8);
    *(int4*)&WtS[(size_t)((r << 5) | (c ^ (r & 31))) << 3] = v;
  }
  __syncthreads();

  const int wave = tid >> 6;
  const int lane = tid & 63;
  const int lm = lane & 15;
  const int kq = lane >> 4;            // 0..3
  const int koff = kq * 8;
  const int quad = kq;

  float bv[8];
#pragma unroll
  for (int nt = 0; nt < 8; ++nt) bv[nt] = bl[nt * 16 + lm];

  const int T = (N + 31) >> 5;
  for (int t = (int)blockIdx.x * 4 + wave; t < T; t += (int)gridDim.x * 4) {
    const int row0 = t * 32;
    size_t abase[2];
#pragma unroll
    for (int a = 0; a < 2; ++a) abase[a] = (size_t)(row0 + a * 16 + lm) * DH;

    f32x4 acc[2][8];
#pragma unroll
    for (int a = 0; a < 2; ++a)
#pragma unroll
      for (int nt = 0; nt < 8; ++nt) acc[a][nt] = (f32x4){0.f, 0.f, 0.f, 0.f};

#pragma unroll
    for (int ks = 0; ks < 8; ++ks) {
      short8 af[2];
#pragma unroll
      for (int a = 0; a < 2; ++a) {
        const ushort_t* p = (ks < 4) ? (A0 + abase[a] + ks * 32 + koff)
                                     : (A1 + abase[a] + (ks - 4) * 32 + koff);
        af[a] = *(const short8*)p;
      }
#pragma unroll
      for (int nt = 0; nt < 8; ++nt) {
        const int r = nt * 16 + lm;
        const int c = (ks * 4 + kq) ^ (r & 31);
        short8 bf = *(const short8*)&WtS[(size_t)((r << 5) | c) << 3];
        acc[0][nt] = __builtin_amdgcn_mfma_f32_16x16x32_bf16(af[0], bf, acc[0][nt], 0, 0, 0);
        acc[1][nt] = __builtin_amdgcn_mfma_f32_16x16x32_bf16(af[1], bf, acc[1][nt], 0, 0, 0);
      }
    }

#pragma unroll
    for (int a = 0; a < 2; ++a) {
#pragma unroll
      for (int reg = 0; reg < 4; ++reg) {
        const int r = row0 + a * 16 + quad * 4 + reg;
        float vv[8];
#pragma unroll
        for (int nt = 0; nt < 8; ++nt)
          vv[nt] = fmaxf(acc[a][nt][reg] + bv[nt], 0.f);
#pragma unroll
        for (int nt = 0; nt < 8; ++nt)
          out[(size_t)r * DH + nt * 16 + lm] = f2bf(vv[nt]);
        if (out8) {
#pragma unroll
          for (int nt = 0; nt < 8; ++nt)
            out8[(size_t)r * DH + nt * 16 + lm] = f2fp8(vv[nt]);
        }
      }
    }
  }
}

// ---------- fused projection GEMMs: pu = ux@Wu, pm = mx@Wm ----------
__device__ __forceinline__ void proj_body(
    int lblk, const ushort_t* __restrict__ A, const ushort_t* __restrict__ Wt,
    int kofs, ushort_t* __restrict__ out, int N)
{
  const int wave = threadIdx.x >> 6;
  const int lane = threadIdx.x & 63;
  const int row0 = (lblk * 4 + wave) * 32;
  if (row0 >= N) return;
  const int lm = lane & 15;
  const int koff = (lane >> 4) * 8;

  size_t abase[2];
#pragma unroll
  for (int a = 0; a < 2; ++a) abase[a] = (size_t)(row0 + a * 16 + lm) * DH;

  f32x4 acc[2][8];
#pragma unroll
  for (int a = 0; a < 2; ++a)
#pragma unroll
    for (int nt = 0; nt < 8; ++nt) acc[a][nt] = (f32x4){0.f, 0.f, 0.f, 0.f};

#pragma unroll
  for (int ks = 0; ks < 4; ++ks) {
    short8 af[2];
#pragma unroll
    for (int a = 0; a < 2; ++a) af[a] = *(const short8*)(A + abase[a] + ks * 32 + koff);
#pragma unroll
    for (int nt = 0; nt < 8; ++nt) {
      short8 bf = *(const short8*)&Wt[(nt * 16 + lm) * 256 + kofs + ks * 32 + koff];
      acc[0][nt] = __builtin_amdgcn_mfma_f32_16x16x32_bf16(af[0], bf, acc[0][nt], 0, 0, 0);
      acc[1][nt] = __builtin_amdgcn_mfma_f32_16x16x32_bf16(af[1], bf, acc[1][nt], 0, 0, 0);
    }
  }

  const int quad = lane >> 4;
#pragma unroll
  for (int a = 0; a < 2; ++a) {
#pragma unroll
    for (int reg = 0; reg < 4; ++reg) {
      const int r = row0 + a * 16 + quad * 4 + reg;
#pragma unroll
      for (int nt = 0; nt < 8; ++nt)
        out[(size_t)r * DH + nt * 16 + lm] = f2bf(acc[a][nt][reg]);
    }
  }
}

__global__ __launch_bounds__(256) void proj2_k(
    const ushort_t* __restrict__ ux, const ushort_t* __restrict__ mx,
    const ushort_t* __restrict__ Wt, ushort_t* __restrict__ pu,
    ushort_t* __restrict__ pm, int gmU)
{
  if ((int)blockIdx.x < gmU) proj_body(blockIdx.x, ux, Wt, 0, pu, NUSR);
  else proj_body(blockIdx.x - gmU, mx, Wt, DH, pm, NMOV);
}

// ---------- bucket-parallel predictor: 32 slices/bin, 10 movie-subbin passes ----------
__global__ __launch_bounds__(256) void ep_bkt_k(
    const ushort_t* __restrict__ pu, const ushort_t* __restrict__ pm,
    const uint2* __restrict__ bkt_s2, const int* __restrict__ bcnt,
    const float* __restrict__ SEP, const float* __restrict__ TEP,
    const float* __restrict__ p2W, const float* __restrict__ p2b,
    float* __restrict__ out)
{
  const int b = (int)blockIdx.x & 127;
  const int sl = (int)blockIdx.x >> 7;     // 0..EPSL-1 (XCD = b%8 for all sl)
  const int tid = threadIdx.x;
  const int lm = tid & 15;
  const int qw = tid >> 4;                 // 0..15
  const int f0 = lm * 8;

  float S[8], T8[8], w2[8];
#pragma unroll
  for (int j = 0; j < 8; ++j) {
    S[j] = SEP[f0 + j];
    T8[j] = TEP[f0 + j];
    w2[j] = p2W[f0 + j];
  }
  const float bias2 = p2b[0];

  int n = bcnt[NBD + b];
  if (n > BKS) n = BKS;
  const uint2* B = bkt_s2 + (size_t)b * BKS;
  const int ub = b * WS;
  const int chunk = (n + EPSL - 1) / EPSL;
  const int st = sl * chunk;
  int en = st + chunk;
  if (en > n) en = n;

  for (int sb = 0; sb < NSB; ++sb) {
    for (int i = st + qw; i < en; i += 16) {
      uint2 ent = B[i];
      int d = (int)(ent.x >> 10);
      if ((d >> 11) != sb) continue;       // quarter-wave-uniform test
      int s = ub + (int)(ent.x & 1023u);
      int4 uv = *(const int4*)(pu + (s << 7) + f0);
      int4 mv = *(const int4*)(pm + (d << 7) + f0);
      float fu[8], fm[8];
      {
        unsigned a0 = (unsigned)uv.x, b0 = (unsigned)uv.y, c0 = (unsigned)uv.z, d0 = (unsigned)uv.w;
        fu[0] = __uint_as_float(a0 << 16); fu[1] = __uint_as_float(a0 & 0xFFFF0000u);
        fu[2] = __uint_as_float(b0 << 16); fu[3] = __uint_as_float(b0 & 0xFFFF0000u);
        fu[4] = __uint_as_float(c0 << 16); fu[5] = __uint_as_float(c0 & 0xFFFF0000u);
        fu[6] = __uint_as_float(d0 << 16); fu[7] = __uint_as_float(d0 & 0xFFFF0000u);
        unsigned a1 = (unsigned)mv.x, b1 = (unsigned)mv.y, c1 = (unsigned)mv.z, d1 = (unsigned)mv.w;
        fm[0] = __uint_as_float(a1 << 16); fm[1] = __uint_as_float(a1 & 0xFFFF0000u);
        fm[2] = __uint_as_float(b1 << 16); fm[3] = __uint_as_float(b1 & 0xFFFF0000u);
        fm[4] = __uint_as_float(c1 << 16); fm[5] = __uint_as_float(c1 & 0xFFFF0000u);
        fm[6] = __uint_as_float(d1 << 16); fm[7] = __uint_as_float(d1 & 0xFFFF0000u);
      }
      float p = 0.f;
#pragma unroll
      for (int j = 0; j < 8; ++j) {
        float h = fmaxf(fmaf(fu[j] + fm[j], S[j], T8[j]), 0.f);
        p = fmaf(h, w2[j], p);
      }
      p += __shfl_xor(p, 1, 16);
      p += __shfl_xor(p, 2, 16);
      p += __shfl_xor(p, 4, 16);
      p += __shfl_xor(p, 8, 16);
      if (lm == 0)
        __builtin_nontemporal_store(4.f / (1.f + expf(-(p + bias2))) + 1.f, &out[ent.y]);
    }
  }
}

extern "C" void kernel_launch(void* const* d_in, const int* in_sizes, int n_in,
                              void* d_out, int out_size, void* d_ws, size_t ws_size,
                              hipStream_t stream)
{
  const float* user_feat = (const float*)d_in[0];
  const float* movie_feat = (const float*)d_in[1];
  const float* W_user = (const float*)d_in[2];
  const float* b_user = (const float*)d_in[3];
  const float* W_movie = (const float*)d_in[4];
  const float* b_movie = (const float*)d_in[5];
  const float* u2m1_Wl = (const float*)d_in[6];
  const float* u2m1_bl = (const float*)d_in[7];
  const float* u2m1_Wr = (const float*)d_in[8];
  const float* m2u1_Wl = (const float*)d_in[9];
  const float* m2u1_bl = (const float*)d_in[10];
  const float* m2u1_Wr = (const float*)d_in[11];
  const float* u2m2_Wl = (const float*)d_in[12];
  const float* u2m2_bl = (const float*)d_in[13];
  const float* u2m2_Wr = (const float*)d_in[14];
  const float* m2u2_Wl = (const float*)d_in[15];
  const float* m2u2_bl = (const float*)d_in[16];
  const float* m2u2_Wr = (const float*)d_in[17];
  const float* u2u_Wl = (const float*)d_in[18];
  const float* u2u_bl = (const float*)d_in[19];
  const float* u2u_Wr = (const float*)d_in[20];
  const float* p1_W = (const float*)d_in[21];
  const float* p1_b = (const float*)d_in[22];
  const float* bn_gamma = (const float*)d_in[23];
  const float* bn_beta = (const float*)d_in[24];
  const float* bn_mean = (const float*)d_in[25];
  const float* bn_var = (const float*)d_in[26];
  const float* p2_W = (const float*)d_in[27];
  const float* p2_b = (const float*)d_in[28];
  const int* rated_src = (const int*)d_in[29];
  const int* rated_dst = (const int*)d_in[30];
  const int* uu_src = (const int*)d_in[31];
  const int* uu_dst = (const int*)d_in[32];

  // ---- workspace layout (~110.5 MB; known-good footprint is 113 MB) ----
  ushort_t* ux = (ushort_t*)d_ws;                       // NU*128 bf16
  ushort_t* mx = ux + (size_t)NUSR * DH;                // NM*128
  ushort_t* agg = mx + (size_t)NMOV * DH;               // NU*128 (pu; bkt_d/bkt_u alias pre-fill)
  ushort_t* pm = agg + (size_t)NUSR * DH;               // NM*128
  ushort_t* Wt = pm + (size_t)NMOV * DH;                // 6 * 32768
  ushort_t* WtU = Wt + 6 * 32768;                       // 128*64
  ushort_t* WtM = WtU + 8192;                           // 128*128
  float* SEP = (float*)(WtM + 16384);                   // 128
  float* TEP = SEP + DH;                                // 128
  int* col_m = (int*)(TEP + DH);                        // NMOV*CAPM ints
  ushort_t* col_u = (ushort_t*)(col_m + (size_t)NMOV * CAPM);   // NUSR*CAPU ushorts
  int* col_uu = (int*)(col_u + (size_t)NUSR * CAPU);    // NUSR*CAPUU ints
  int* cntbuf = col_uu + (size_t)NUSR * CAPUU;          // NMOV+2*NUSR+NBT
  uchar_t* ux8 = (uchar_t*)(cntbuf + (NMOV + 2 * NUSR + NBT));  // NU*128 fp8
  uchar_t* mx8 = ux8 + (size_t)NUSR * DH;               // NM*128 fp8
  uint2* bkt_s2 = (uint2*)(mx8 + (size_t)NMOV * DH);    // 128*BKS uint2 (8.65MB, survives to ep)
  int* cnt_m = cntbuf;
  int* cnt_u = cntbuf + NMOV;
  int* cnt_uu = cntbuf + NMOV + NUSR;
  int* bcnt = cntbuf + NMOV + 2 * NUSR;                 // NBT bucket cursors

  // d/u edge buckets alias agg (6.6MB < 25.6MB; both drained by csr_k which
  // runs before the first agg_mean4_k write to agg)
  unsigned* bkt_d = (unsigned*)agg;
  unsigned* bkt_u = bkt_d + (size_t)NBD * BKD;

  ushort_t* Wt_u2m1 = Wt + 0 * 32768;
  ushort_t* Wt_m2u1 = Wt + 1 * 32768;
  ushort_t* Wt_u2m2 = Wt + 2 * 32768;
  ushort_t* Wt_m2u2 = Wt + 3 * 32768;
  ushort_t* Wt_u2u  = Wt + 4 * 32768;
  ushort_t* Wt_p1   = Wt + 5 * 32768;
  ushort_t* pu = agg;  // alias: agg dead after last sage layer

  // ---- fused weight prep + BN params + bcnt zero ----
  PrepArgs pa;
  pa.Wl[0] = u2m1_Wl; pa.Wr[0] = u2m1_Wr;
  pa.Wl[1] = m2u1_Wl; pa.Wr[1] = m2u1_Wr;
  pa.Wl[2] = u2m2_Wl; pa.Wr[2] = u2m2_Wr;
  pa.Wl[3] = m2u2_Wl; pa.Wr[3] = m2u2_Wr;
  pa.Wl[4] = u2u_Wl;  pa.Wr[4] = u2u_Wr;
  pa.Wl[5] = p1_W;    pa.Wr[5] = p1_W + DH * DH;
  prep_all_k<<<865, 256, 0, stream>>>(
      pa, Wt, W_user, W_movie, WtU, WtM,
      p1_b, bn_gamma, bn_beta, bn_mean, bn_var, SEP, TEP, bcnt);

  // ---- two-phase fill (fine bins -> LDS CSR assembly), then input linears ----
  bin_rated_k<<<NBINB, 256, 0, stream>>>(
      rated_src, rated_dst, bkt_d, bkt_s2, bcnt);
  bin_uu_k<<<NBINB, 256, 0, stream>>>(uu_src, uu_dst, bkt_u, bcnt);
  csr_k<<<NBT, 256, 0, stream>>>(
      bkt_d, bkt_s2, bkt_u, bcnt, cnt_m, cnt_u, cnt_uu, col_m, col_u, col_uu);
  lin2_k<<<GLU + GLM, 256, 0, stream>>>(
      user_feat, WtU, b_user, ux, ux8, movie_feat, WtM, b_movie, mx, mx8);

  // ---- 5 SAGE layers (fp8 gather + LDS-staged-Wt MFMA) ----
  const int gaM = (NMOV + 15) / 16, gaU = (NUSR + 15) / 16;
  // u2m1: gather ux8 -> agg; update mx (+mx8, needed by m2u1 agg)
  agg_mean4_k<int, CAPM, 16><<<gaM, 256, 0, stream>>>(ux8, cnt_m, col_m, agg, NMOV);
  sage_mfma_k<<<GSM, 256, 0, stream>>>(agg, mx, Wt_u2m1, u2m1_bl, mx, mx8, NMOV);
  // m2u1: gather mx8 -> agg; update ux (+ux8, needed by u2m2 agg)
  agg_mean4_k<ushort_t, CAPU, 8><<<gaU, 256, 0, stream>>>(mx8, cnt_u, col_u, agg, NUSR);
  sage_mfma_k<<<GSU, 256, 0, stream>>>(agg, ux, Wt_m2u1, m2u1_bl, ux, ux8, NUSR);
  // u2m2
  agg_mean4_k<int, CAPM, 16><<<gaM, 256, 0, stream>>>(ux8, cnt_m, col_m, agg, NMOV);
  sage_mfma_k<<<GSM, 256, 0, stream>>>(agg, mx, Wt_u2m2, u2m2_bl, mx, mx8, NMOV);
  // m2u2
  agg_mean4_k<ushort_t, CAPU, 8><<<gaU, 256, 0, stream>>>(mx8, cnt_u, col_u, agg, NUSR);
  sage_mfma_k<<<GSU, 256, 0, stream>>>(agg, ux, Wt_m2u2, m2u2_bl, ux, ux8, NUSR);
  // u2u: final user layer; fp8 copy no longer needed afterwards
  agg_mean4_k<int, CAPUU, 8><<<gaU, 256, 0, stream>>>(ux8, cnt_uu, col_uu, agg, NUSR);
  sage_mfma_k<<<GSU, 256, 0, stream>>>(agg, ux, Wt_u2u, u2u_bl, ux, (uchar_t*)nullptr, NUSR);

  // ---- factored edge MLP (bf16 throughout; bucket-ordered predictor) ----
  const int gmU = (NUSR + 127) / 128, gmM = (NMOV + 127) / 128;
  proj2_k<<<gmU + gmM, 256, 0, stream>>>(ux, mx, Wt_p1, pu, pm, gmU);
  ep_bkt_k<<<NEPB, 256, 0, stream>>>(
      pu, pm, bkt_s2, bcnt, SEP, TEP, p2_W, p2_b, (float*)d_out);
}

// Round 10
// 551.939 us; speedup vs baseline: 1.3652x; 1.2528x over previous
//
#include <hip/hip_runtime.h>
#include <cmath>

// SimpleHeteroGNN on MI355X — Round 26.
// R25 post-mortem: 10-subbin ep re-scan cost ~20us/pass scan overhead (VALU
// 82%, dur 200us) >> 15us of saved HBM. Multi-pass is dead. REVERT ep to the
// single-pass R23 form (560us proven). New: (1) fold BN S into Wt_p1 columns
// (prep) and T into pm's projection bias -> ep inner loop loses 8 FMA/octet
// + S/T loads; (2) 4-edge ILP in ep (8 rows in flight before unpack).

#define NUSR 100000
#define NMOV 20000
#define NEDG 1000000
#define NEUU 500000
#define DH 128

// padded adjacency capacities (degree means 50/10/5; >=6.5 sigma)
#define CAPM 96
#define CAPU 32
#define CAPUU 24

// fine binning geometry
#define NBD 128
#define WD 157            // 128*157 >= 20000; 157*96*4B = 60288B LDS (csr)
#define NBS 128
#define WS 782            // 128*782 >= 100000
#define NBU 196
#define WU 512
#define NBT (NBD + NBS + NBU)  // 452

// per-block LDS staging caps (lambda 8/8/2.6; ~+10 sigma)
#define LCD 36
#define LCS 36
#define LCU 20
// global bucket caps (mean 7812/7812/2551; +7 sigma)
#define BKD 8448
#define BKS 8448
#define BKU 2944

#define NBINB 977         // 977*1024 >= NEDG, 977*512 >= NEUU
#define EPSL 32           // ep slices per bin
#define NEPB (EPSL * 128) // 4096 ep blocks

// block ranges
#define GLU ((NUSR + 127) / 128)        // 782  (lin: 32 rows/wave)
#define GLM ((NMOV + 127) / 128)        // 157
#define GSU 512                         // sage user: 3125 tiles, 2 blocks/CU
#define GSM 157                         // sage movie: 625 tiles

typedef unsigned short ushort_t;
typedef unsigned char uchar_t;
typedef __attribute__((ext_vector_type(8))) short short8;
typedef __attribute__((ext_vector_type(4))) float f32x4;
typedef __attribute__((ext_vector_type(2))) float f32x2;

__device__ __forceinline__ ushort_t f2bf(float f) {
  unsigned u = __float_as_uint(f);
  u += 0x7FFFu + ((u >> 16) & 1u);
  return (ushort_t)(u >> 16);
}
__device__ __forceinline__ uchar_t f2fp8(float v) {
  return (uchar_t)(__builtin_amdgcn_cvt_pk_fp8_f32(v, v, 0, false) & 0xFF);
}
__device__ __forceinline__ void fp8x8_to_f32(uint2 v, float* f) {
  f32x2 a = __builtin_amdgcn_cvt_pk_f32_fp8((int)v.x, false);
  f32x2 b = __builtin_amdgcn_cvt_pk_f32_fp8((int)v.x, true);
  f32x2 c = __builtin_amdgcn_cvt_pk_f32_fp8((int)v.y, false);
  f32x2 d = __builtin_amdgcn_cvt_pk_f32_fp8((int)v.y, true);
  f[0] = a.x; f[1] = a.y; f[2] = b.x; f[3] = b.y;
  f[4] = c.x; f[5] = c.y; f[6] = d.x; f[7] = d.y;
}
__device__ __forceinline__ void bf2x8(int4 v, float* f) {
  unsigned a = (unsigned)v.x, b = (unsigned)v.y, c = (unsigned)v.z, d = (unsigned)v.w;
  f[0] = __uint_as_float(a << 16); f[1] = __uint_as_float(a & 0xFFFF0000u);
  f[2] = __uint_as_float(b << 16); f[3] = __uint_as_float(b & 0xFFFF0000u);
  f[4] = __uint_as_float(c << 16); f[5] = __uint_as_float(c & 0xFFFF0000u);
  f[6] = __uint_as_float(d << 16); f[7] = __uint_as_float(d & 0xFFFF0000u);
}
__device__ __forceinline__ int ntl(const int* p) { return __builtin_nontemporal_load(p); }
__device__ __forceinline__ unsigned ntl(const unsigned* p) { return __builtin_nontemporal_load(p); }
__device__ __forceinline__ ushort_t ntl(const ushort_t* p) { return __builtin_nontemporal_load(p); }

// ---------- fused weight prep + BN params + bcnt zero ----------
// wi==5 (p1) columns are pre-scaled by S[n] = gamma*rsqrt(var+eps); T goes
// into pm's projection bias (TEP).
struct PrepArgs {
  const float* Wl[6];
  const float* Wr[6];
};
__global__ __launch_bounds__(256) void prep_all_k(
    PrepArgs pa, ushort_t* __restrict__ Wt,
    const float* __restrict__ W_user, const float* __restrict__ W_movie,
    ushort_t* __restrict__ WtU, ushort_t* __restrict__ WtM,
    const float* __restrict__ p1b, const float* __restrict__ gamma,
    const float* __restrict__ beta, const float* __restrict__ mean,
    const float* __restrict__ var,
    float* __restrict__ SEP, float* __restrict__ TEP,
    int* __restrict__ bcnt)
{
  int blk = blockIdx.x;
  if (blk < 768) {
    int wi = blk >> 7;
    int idx = (blk & 127) * 256 + threadIdx.x;
    int n = idx >> 8, k = idx & 255;
    const float* Wl = pa.Wl[wi];
    const float* Wr = pa.Wr[wi];
    float v = (k < DH) ? Wl[k * DH + n] : Wr[(k - DH) * DH + n];
    if (wi == 5) v *= gamma[n] * rsqrtf(var[n] + 1e-5f);
    Wt[(size_t)wi * 32768 + n * 256 + k] = f2bf(v);
  } else if (blk < 800) {
    int idx = (blk - 768) * 256 + threadIdx.x;
    int n = idx >> 6, k = idx & 63;
    WtU[n * 64 + k] = f2bf(W_user[k * DH + n]);
  } else if (blk < 864) {
    int idx = (blk - 800) * 256 + threadIdx.x;
    int n = idx >> 7, k = idx & 127;
    WtM[n * 128 + k] = f2bf(W_movie[k * DH + n]);
  } else {
    int f = threadIdx.x;
    if (f < DH) {
      float sc = gamma[f] * rsqrtf(var[f] + 1e-5f);
      SEP[f] = sc;
      TEP[f] = (p1b[f] - mean[f]) * sc + beta[f];
    }
    for (int i = threadIdx.x; i < NBT; i += 256) bcnt[i] = 0;
  }
}

// ---------- phase A1: bin rated edges (d-bins 4B, s-bins 8B with eid) ----------
__global__ __launch_bounds__(256) void bin_rated_k(
    const int* __restrict__ rsrc, const int* __restrict__ rdst,
    unsigned* __restrict__ bkt_d, uint2* __restrict__ bkt_s2,
    int* __restrict__ bcnt)
{
  __shared__ unsigned sb_d[NBD * LCD];
  __shared__ uint2 sb_s[NBS * LCS];
  __shared__ int lcnt[NBD + NBS];
  __shared__ int gbase[NBD + NBS];
  const int tid = threadIdx.x;
  for (int i = tid; i < NBD + NBS; i += 256) lcnt[i] = 0;
  __syncthreads();
  const int c = blockIdx.x;
#pragma unroll
  for (int it = 0; it < 4; ++it) {
    int e = c * 1024 + it * 256 + tid;
    if (e < NEDG) {
      int s = ntl(&rsrc[e]), d = ntl(&rdst[e]);
      int bd = d / WD;
      int o = atomicAdd(&lcnt[bd], 1);
      if (o < LCD) sb_d[bd * LCD + o] = (unsigned)(d - bd * WD) | ((unsigned)s << 8);
      int bs = s / WS;
      int o2 = atomicAdd(&lcnt[NBD + bs], 1);
      if (o2 < LCS)
        sb_s[bs * LCS + o2] =
            make_uint2((unsigned)(s - bs * WS) | ((unsigned)d << 10), (unsigned)e);
    }
  }
  __syncthreads();
  for (int i = tid; i < NBD + NBS; i += 256) {
    int n = lcnt[i];
    if (n > LCD) n = LCD;   // LCD == LCS
    lcnt[i] = n;
    gbase[i] = atomicAdd(&bcnt[i], n);
  }
  __syncthreads();
  const int qw = tid >> 4, lq = tid & 15;
  for (int t = qw; t < NBD + NBS; t += 16) {
    int n = lcnt[t], gb = gbase[t];
    if (t < NBD) {
      if (gb + n > BKD) n = BKD - gb;
      unsigned* gp = bkt_d + (size_t)t * BKD;
      const unsigned* sp = sb_d + t * LCD;
      for (int i = lq; i < n; i += 16) gp[gb + i] = sp[i];
    } else {
      int b = t - NBD;
      if (gb + n > BKS) n = BKS - gb;
      uint2* gp = bkt_s2 + (size_t)b * BKS;
      const uint2* sp = sb_s + b * LCS;
      for (int i = lq; i < n; i += 16) gp[gb + i] = sp[i];
    }
  }
}

// ---------- phase A2: bin uu edges ----------
__global__ __launch_bounds__(256) void bin_uu_k(
    const int* __restrict__ usrc, const int* __restrict__ udst,
    unsigned* __restrict__ bkt_u, int* __restrict__ bcnt)
{
  __shared__ unsigned sb_u[NBU * LCU];
  __shared__ int lcnt[NBU];
  __shared__ int gbase[NBU];
  const int tid = threadIdx.x;
  for (int i = tid; i < NBU; i += 256) lcnt[i] = 0;
  __syncthreads();
  const int c = blockIdx.x;
#pragma unroll
  for (int it = 0; it < 2; ++it) {
    int e = c * 512 + it * 256 + tid;
    if (e < NEUU) {
      int s = ntl(&usrc[e]), d = ntl(&udst[e]);
      int bu = d >> 9;
      int o = atomicAdd(&lcnt[bu], 1);
      if (o < LCU) sb_u[bu * LCU + o] = (unsigned)(d & 511) | ((unsigned)s << 9);
    }
  }
  __syncthreads();
  for (int i = tid; i < NBU; i += 256) {
    int n = lcnt[i];
    if (n > LCU) n = LCU;
    lcnt[i] = n;
    gbase[i] = atomicAdd(&bcnt[NBD + NBS + i], n);
  }
  __syncthreads();
  const int qw = tid >> 4, lq = tid & 15;
  for (int t = qw; t < NBU; t += 16) {
    int n = lcnt[t], gb = gbase[t];
    if (gb + n > BKU) n = BKU - gb;
    unsigned* gp = bkt_u + (size_t)t * BKU;
    const unsigned* sp = sb_u + t * LCU;
    for (int i = lq; i < n; i += 16) gp[gb + i] = sp[i];
  }
}

// ---------- phase B: build CSR slice fully in LDS, flush coalesced ----------
__global__ __launch_bounds__(256) void csr_k(
    const unsigned* __restrict__ bkt_d, const uint2* __restrict__ bkt_s2,
    const unsigned* __restrict__ bkt_u, const int* __restrict__ bcnt,
    int* __restrict__ cnt_m, int* __restrict__ cnt_u, int* __restrict__ cnt_uu,
    int* __restrict__ col_m, ushort_t* __restrict__ col_u, int* __restrict__ col_uu)
{
  __shared__ int lc[WS];                               // 782 ints (max rows/bin)
  __shared__ alignas(16) unsigned cbuf[WD * CAPM];     // 60288B (max slice)
  const int tid = threadIdx.x;
  const int bid = blockIdx.x;
  if (bid < NBD) {
    const int b = bid;
    const int nr = (NMOV - b * WD < WD) ? (NMOV - b * WD) : WD;
    for (int m = tid; m < nr; m += 256) lc[m] = 0;
    __syncthreads();
    int n = bcnt[b]; if (n > BKD) n = BKD;
    const unsigned* B = bkt_d + (size_t)b * BKD;
    for (int i = tid; i < n; i += 256) {
      unsigned v = ntl(&B[i]);
      int m = (int)(v & 255u);
      int o = atomicAdd(&lc[m], 1);
      if (o < CAPM) cbuf[m * CAPM + o] = v >> 8;
    }
    __syncthreads();
    for (int m = tid; m < nr; m += 256) cnt_m[b * WD + m] = lc[m];
    int4* dst = (int4*)(col_m + (size_t)b * WD * CAPM);
    const int4* src = (const int4*)cbuf;
    const int tot = nr * (CAPM / 4);
    for (int i = tid; i < tot; i += 256) dst[i] = src[i];
  } else if (bid < NBD + NBS) {
    const int b = bid - NBD;
    const int nr = (NUSR - b * WS < WS) ? (NUSR - b * WS) : WS;
    for (int u = tid; u < nr; u += 256) lc[u] = 0;
    __syncthreads();
    int n = bcnt[NBD + b]; if (n > BKS) n = BKS;
    const uint2* B = bkt_s2 + (size_t)b * BKS;
    ushort_t* cb16 = (ushort_t*)cbuf;
    for (int i = tid; i < n; i += 256) {
      unsigned v = B[i].x;
      int u = (int)(v & 1023u);
      int o = atomicAdd(&lc[u], 1);
      if (o < CAPU) cb16[u * CAPU + o] = (ushort_t)(v >> 10);
    }
    __syncthreads();
    for (int u = tid; u < nr; u += 256) cnt_u[b * WS + u] = lc[u];
    int4* dst = (int4*)(col_u + (size_t)b * WS * CAPU);
    const int4* src = (const int4*)cbuf;
    const int tot = nr * (CAPU / 8);                   // nr*64B / 16
    for (int i = tid; i < tot; i += 256) dst[i] = src[i];
  } else {
    const int b = bid - NBD - NBS;
    const int nr = (NUSR - b * WU < WU) ? (NUSR - b * WU) : WU;
    for (int u = tid; u < nr; u += 256) lc[u] = 0;
    __syncthreads();
    int n = bcnt[NBD + NBS + b]; if (n > BKU) n = BKU;
    const unsigned* B = bkt_u + (size_t)b * BKU;
    for (int i = tid; i < n; i += 256) {
      unsigned v = ntl(&B[i]);
      int u = (int)(v & 511u);
      int o = atomicAdd(&lc[u], 1);
      if (o < CAPUU) cbuf[u * CAPUU + o] = v >> 9;
    }
    __syncthreads();
    for (int u = tid; u < nr; u += 256) cnt_uu[b * WU + u] = lc[u];
    int4* dst = (int4*)(col_uu + (size_t)b * WU * CAPUU);
    const int4* src = (const int4*)cbuf;
    const int tot = nr * (CAPUU / 4);
    for (int i = tid; i < tot; i += 256) dst[i] = src[i];
  }
}

// ---------- lin GEMM body (fp32 A converted in-register; bf16 + fp8 out) ----------
template <int K>
__device__ __forceinline__ void lin_body(
    int lblk, const float* __restrict__ X, const ushort_t* __restrict__ Wt,
    const float* __restrict__ b, ushort_t* __restrict__ Y,
    uchar_t* __restrict__ Y8, int N)
{
  const int wave = threadIdx.x >> 6;
  const int lane = threadIdx.x & 63;
  const int row0 = (lblk * 4 + wave) * 32;
  if (row0 >= N) return;
  const int lm = lane & 15;
  const int koff = (lane >> 4) * 8;

  f32x4 acc[2][8];
#pragma unroll
  for (int a = 0; a < 2; ++a)
#pragma unroll
    for (int nt = 0; nt < 8; ++nt) acc[a][nt] = (f32x4){0.f, 0.f, 0.f, 0.f};

#pragma unroll
  for (int ks = 0; ks < K / 32; ++ks) {
    short8 af[2];
#pragma unroll
    for (int a = 0; a < 2; ++a) {
      const float* p = X + (size_t)(row0 + a * 16 + lm) * K + ks * 32 + koff;
      float4 v0 = *(const float4*)p;
      float4 v1 = *(const float4*)(p + 4);
      short8 s;
      s[0] = (short)f2bf(v0.x); s[1] = (short)f2bf(v0.y);
      s[2] = (short)f2bf(v0.z); s[3] = (short)f2bf(v0.w);
      s[4] = (short)f2bf(v1.x); s[5] = (short)f2bf(v1.y);
      s[6] = (short)f2bf(v1.z); s[7] = (short)f2bf(v1.w);
      af[a] = s;
    }
#pragma unroll
    for (int nt = 0; nt < 8; ++nt) {
      short8 bf = *(const short8*)&Wt[(nt * 16 + lm) * K + ks * 32 + koff];
      acc[0][nt] = __builtin_amdgcn_mfma_f32_16x16x32_bf16(af[0], bf, acc[0][nt], 0, 0, 0);
      acc[1][nt] = __builtin_amdgcn_mfma_f32_16x16x32_bf16(af[1], bf, acc[1][nt], 0, 0, 0);
    }
  }

  const int quad = lane >> 4;
  float bv[8];
#pragma unroll
  for (int nt = 0; nt < 8; ++nt) bv[nt] = b[nt * 16 + lm];
#pragma unroll
  for (int a = 0; a < 2; ++a) {
#pragma unroll
    for (int reg = 0; reg < 4; ++reg) {
      const int r = row0 + a * 16 + quad * 4 + reg;
      float vv[8];
#pragma unroll
      for (int nt = 0; nt < 8; ++nt)
        vv[nt] = fmaxf(acc[a][nt][reg] + bv[nt], 0.f);
#pragma unroll
      for (int nt = 0; nt < 8; ++nt)
        Y[(size_t)r * DH + nt * 16 + lm] = f2bf(vv[nt]);
#pragma unroll
      for (int nt = 0; nt < 8; ++nt)
        Y8[(size_t)r * DH + nt * 16 + lm] = f2fp8(vv[nt]);
    }
  }
}

// ---------- both input linears in one dispatch ----------
__global__ __launch_bounds__(256) void lin2_k(
    const float* __restrict__ user_feat, const ushort_t* __restrict__ WtU,
    const float* __restrict__ b_user, ushort_t* __restrict__ ux, uchar_t* __restrict__ ux8,
    const float* __restrict__ movie_feat, const ushort_t* __restrict__ WtM,
    const float* __restrict__ b_movie, ushort_t* __restrict__ mx, uchar_t* __restrict__ mx8)
{
  const int blk = blockIdx.x;
  if (blk < GLU) lin_body<64>(blk, user_feat, WtU, b_user, ux, ux8, NUSR);
  else lin_body<128>(blk - GLU, movie_feat, WtM, b_movie, mx, mx8, NMOV);
}

// ---------- gather-mean over padded adjacency, fp8 source: 4 rows/wave ----------
template <typename CT, int CAP, int UNR>
__global__ __launch_bounds__(256) void agg_mean4_k(
    const uchar_t* __restrict__ x8, const int* __restrict__ cnt,
    const CT* __restrict__ col, ushort_t* __restrict__ out, int N)
{
  const int wave = threadIdx.x >> 6;
  const int lane = threadIdx.x & 63;
  const int lm = lane & 15, q = lane >> 4;
  const int row = blockIdx.x * 16 + wave * 4 + q;
  if (row >= N) return;
  const int deg = cnt[row];
  const int e = (deg < CAP) ? deg : CAP;
  const CT* crow = col + (size_t)row * CAP;
  float a[8];
#pragma unroll
  for (int j = 0; j < 8; ++j) a[j] = 0.f;
  int i = 0;
  if (UNR >= 16) {
    for (; i + 15 < e; i += 16) {
      uint2 v[16];
#pragma unroll
      for (int u = 0; u < 16; ++u) {
        int s = (int)ntl(&crow[i + u]);
        v[u] = *(const uint2*)(x8 + (size_t)s * DH + lm * 8);
      }
#pragma unroll
      for (int u = 0; u < 16; ++u) {
        float f0[8];
        fp8x8_to_f32(v[u], f0);
#pragma unroll
        for (int j = 0; j < 8; ++j) a[j] += f0[j];
      }
    }
  }
  if (UNR >= 8) {
    for (; i + 7 < e; i += 8) {
      uint2 v[8];
#pragma unroll
      for (int u = 0; u < 8; ++u) {
        int s = (int)ntl(&crow[i + u]);
        v[u] = *(const uint2*)(x8 + (size_t)s * DH + lm * 8);
      }
#pragma unroll
      for (int u = 0; u < 8; ++u) {
        float f0[8];
        fp8x8_to_f32(v[u], f0);
#pragma unroll
        for (int j = 0; j < 8; ++j) a[j] += f0[j];
      }
    }
  }
  for (; i + 3 < e; i += 4) {
    uint2 v0, v1, v2, v3;
    int s0 = (int)ntl(&crow[i]), s1 = (int)ntl(&crow[i + 1]);
    int s2 = (int)ntl(&crow[i + 2]), s3 = (int)ntl(&crow[i + 3]);
    v0 = *(const uint2*)(x8 + (size_t)s0 * DH + lm * 8);
    v1 = *(const uint2*)(x8 + (size_t)s1 * DH + lm * 8);
    v2 = *(const uint2*)(x8 + (size_t)s2 * DH + lm * 8);
    v3 = *(const uint2*)(x8 + (size_t)s3 * DH + lm * 8);
    float f0[8], f1[8], f2[8], f3[8];
    fp8x8_to_f32(v0, f0); fp8x8_to_f32(v1, f1);
    fp8x8_to_f32(v2, f2); fp8x8_to_f32(v3, f3);
#pragma unroll
    for (int j = 0; j < 8; ++j) a[j] += (f0[j] + f1[j]) + (f2[j] + f3[j]);
  }
  for (; i < e; ++i) {
    uint2 v0 = *(const uint2*)(x8 + (size_t)(int)ntl(&crow[i]) * DH + lm * 8);
    float f0[8];
    fp8x8_to_f32(v0, f0);
#pragma unroll
    for (int j = 0; j < 8; ++j) a[j] += f0[j];
  }
  float inv = 1.f / (float)(deg > 1 ? deg : 1);
  unsigned p0 = f2bf(a[0] * inv) | ((unsigned)f2bf(a[1] * inv) << 16);
  unsigned p1 = f2bf(a[2] * inv) | ((unsigned)f2bf(a[3] * inv) << 16);
  unsigned p2 = f2bf(a[4] * inv) | ((unsigned)f2bf(a[5] * inv) << 16);
  unsigned p3 = f2bf(a[6] * inv) | ((unsigned)f2bf(a[7] * inv) << 16);
  *(int4*)(out + (size_t)row * DH + lm * 8) = make_int4(p0, p1, p2, p3);
}

// ---------- SAGE update GEMM: Wt staged in LDS (swizzled), grid-strided ----------
__global__ __launch_bounds__(256) void sage_mfma_k(
    const ushort_t* __restrict__ A0, const ushort_t* __restrict__ A1,
    const ushort_t* __restrict__ Wt, const float* __restrict__ bl,
    ushort_t* __restrict__ out, uchar_t* __restrict__ out8, int N)
{
  __shared__ alignas(16) ushort_t WtS[32768];   // 64KB
  const int tid = threadIdx.x;
  for (int f = tid; f < 4096; f += 256) {
    const int r = f >> 5, c = f & 31;
    const int4 v = *(const int4*)(Wt + (size_t)f * 8);
    *(int4*)&WtS[(size_t)((r << 5) | (c ^ (r & 31))) << 3] = v;
  }
  __syncthreads();

  const int wave = tid >> 6;
  const int lane = tid & 63;
  const int lm = lane & 15;
  const int kq = lane >> 4;            // 0..3
  const int koff = kq * 8;
  const int quad = kq;

  float bv[8];
#pragma unroll
  for (int nt = 0; nt < 8; ++nt) bv[nt] = bl[nt * 16 + lm];

  const int T = (N + 31) >> 5;
  for (int t = (int)blockIdx.x * 4 + wave; t < T; t += (int)gridDim.x * 4) {
    const int row0 = t * 32;
    size_t abase[2];
#pragma unroll
    for (int a = 0; a < 2; ++a) abase[a] = (size_t)(row0 + a * 16 + lm) * DH;

    f32x4 acc[2][8];
#pragma unroll
    for (int a = 0; a < 2; ++a)
#pragma unroll
      for (int nt = 0; nt < 8; ++nt) acc[a][nt] = (f32x4){0.f, 0.f, 0.f, 0.f};

#pragma unroll
    for (int ks = 0; ks < 8; ++ks) {
      short8 af[2];
#pragma unroll
      for (int a = 0; a < 2; ++a) {
        const ushort_t* p = (ks < 4) ? (A0 + abase[a] + ks * 32 + koff)
                                     : (A1 + abase[a] + (ks - 4) * 32 + koff);
        af[a] = *(const short8*)p;
      }
#pragma unroll
      for (int nt = 0; nt < 8; ++nt) {
        const int r = nt * 16 + lm;
        const int c = (ks * 4 + kq) ^ (r & 31);
        short8 bf = *(const short8*)&WtS[(size_t)((r << 5) | c) << 3];
        acc[0][nt] = __builtin_amdgcn_mfma_f32_16x16x32_bf16(af[0], bf, acc[0][nt], 0, 0, 0);
        acc[1][nt] = __builtin_amdgcn_mfma_f32_16x16x32_bf16(af[1], bf, acc[1][nt], 0, 0, 0);
      }
    }

#pragma unroll
    for (int a = 0; a < 2; ++a) {
#pragma unroll
      for (int reg = 0; reg < 4; ++reg) {
        const int r = row0 + a * 16 + quad * 4 + reg;
        float vv[8];
#pragma unroll
        for (int nt = 0; nt < 8; ++nt)
          vv[nt] = fmaxf(acc[a][nt][reg] + bv[nt], 0.f);
#pragma unroll
        for (int nt = 0; nt < 8; ++nt)
          out[(size_t)r * DH + nt * 16 + lm] = f2bf(vv[nt]);
        if (out8) {
#pragma unroll
          for (int nt = 0; nt < 8; ++nt)
            out8[(size_t)r * DH + nt * 16 + lm] = f2fp8(vv[nt]);
        }
      }
    }
  }
}

// ---------- fused projection GEMMs: pu = ux@Wu', pm = mx@Wm' + T ----------
__device__ __forceinline__ void proj_body(
    int lblk, const ushort_t* __restrict__ A, const ushort_t* __restrict__ Wt,
    int kofs, const float* __restrict__ bias, ushort_t* __restrict__ out, int N)
{
  const int wave = threadIdx.x >> 6;
  const int lane = threadIdx.x & 63;
  const int row0 = (lblk * 4 + wave) * 32;
  if (row0 >= N) return;
  const int lm = lane & 15;
  const int koff = (lane >> 4) * 8;

  size_t abase[2];
#pragma unroll
  for (int a = 0; a < 2; ++a) abase[a] = (size_t)(row0 + a * 16 + lm) * DH;

  f32x4 acc[2][8];
#pragma unroll
  for (int a = 0; a < 2; ++a)
#pragma unroll
    for (int nt = 0; nt < 8; ++nt) acc[a][nt] = (f32x4){0.f, 0.f, 0.f, 0.f};

#pragma unroll
  for (int ks = 0; ks < 4; ++ks) {
    short8 af[2];
#pragma unroll
    for (int a = 0; a < 2; ++a) af[a] = *(const short8*)(A + abase[a] + ks * 32 + koff);
#pragma unroll
    for (int nt = 0; nt < 8; ++nt) {
      short8 bf = *(const short8*)&Wt[(nt * 16 + lm) * 256 + kofs + ks * 32 + koff];
      acc[0][nt] = __builtin_amdgcn_mfma_f32_16x16x32_bf16(af[0], bf, acc[0][nt], 0, 0, 0);
      acc[1][nt] = __builtin_amdgcn_mfma_f32_16x16x32_bf16(af[1], bf, acc[1][nt], 0, 0, 0);
    }
  }

  float bb[8];
#pragma unroll
  for (int nt = 0; nt < 8; ++nt) bb[nt] = bias ? bias[nt * 16 + lm] : 0.f;

  const int quad = lane >> 4;
#pragma unroll
  for (int a = 0; a < 2; ++a) {
#pragma unroll
    for (int reg = 0; reg < 4; ++reg) {
      const int r = row0 + a * 16 + quad * 4 + reg;
#pragma unroll
      for (int nt = 0; nt < 8; ++nt)
        out[(size_t)r * DH + nt * 16 + lm] = f2bf(acc[a][nt][reg] + bb[nt]);
    }
  }
}

__global__ __launch_bounds__(256) void proj2_k(
    const ushort_t* __restrict__ ux, const ushort_t* __restrict__ mx,
    const ushort_t* __restrict__ Wt, const float* __restrict__ TEP,
    ushort_t* __restrict__ pu, ushort_t* __restrict__ pm, int gmU)
{
  if ((int)blockIdx.x < gmU) proj_body(blockIdx.x, ux, Wt, 0, nullptr, pu, NUSR);
  else proj_body(blockIdx.x - gmU, mx, Wt, DH, TEP, pm, NMOV);
}

// ---------- bucket-parallel predictor: 32 slices/bin, 4-edge ILP, folded BN ----------
__global__ __launch_bounds__(256) void ep_bkt_k(
    const ushort_t* __restrict__ pu, const ushort_t* __restrict__ pm,
    const uint2* __restrict__ bkt_s2, const int* __restrict__ bcnt,
    const float* __restrict__ p2W, const float* __restrict__ p2b,
    float* __restrict__ out)
{
  const int b = (int)blockIdx.x & 127;
  const int sl = (int)blockIdx.x >> 7;     // 0..EPSL-1 (XCD = b%8 for all sl)
  const int tid = threadIdx.x;
  const int lm = tid & 15;
  const int qw = tid >> 4;                 // 0..15
  const int f0 = lm * 8;

  float w2[8];
#pragma unroll
  for (int j = 0; j < 8; ++j) w2[j] = p2W[f0 + j];
  const float bias2 = p2b[0];

  int n = bcnt[NBD + b];
  if (n > BKS) n = BKS;
  const uint2* B = bkt_s2 + (size_t)b * BKS;
  const int ub = b * WS;
  const int chunk = (n + EPSL - 1) / EPSL;
  const int st = sl * chunk;
  int en = st + chunk;
  if (en > n) en = n;

  for (int i0 = st + qw; i0 < en; i0 += 64) {
    bool vld[4];
    uint2 ent[4];
    int4 uv[4], mv[4];
#pragma unroll
    for (int u = 0; u < 4; ++u) {
      const int ii = i0 + u * 16;
      vld[u] = (ii < en);
      ent[u] = B[vld[u] ? ii : i0];
    }
#pragma unroll
    for (int u = 0; u < 4; ++u) {
      const int s = ub + (int)(ent[u].x & 1023u);
      const int d = (int)(ent[u].x >> 10);
      uv[u] = *(const int4*)(pu + (s << 7) + f0);
      mv[u] = *(const int4*)(pm + (d << 7) + f0);
    }
#pragma unroll
    for (int u = 0; u < 4; ++u) {
      float fu[8], fm[8];
      bf2x8(uv[u], fu);
      bf2x8(mv[u], fm);
      float p = 0.f;
#pragma unroll
      for (int j = 0; j < 8; ++j) {
        float h = fmaxf(fu[j] + fm[j], 0.f);
        p = fmaf(h, w2[j], p);
      }
      p += __shfl_xor(p, 1, 16);
      p += __shfl_xor(p, 2, 16);
      p += __shfl_xor(p, 4, 16);
      p += __shfl_xor(p, 8, 16);
      if (lm == 0 && vld[u])
        __builtin_nontemporal_store(4.f / (1.f + expf(-(p + bias2))) + 1.f, &out[ent[u].y]);
    }
  }
}

extern "C" void kernel_launch(void* const* d_in, const int* in_sizes, int n_in,
                              void* d_out, int out_size, void* d_ws, size_t ws_size,
                              hipStream_t stream)
{
  const float* user_feat = (const float*)d_in[0];
  const float* movie_feat = (const float*)d_in[1];
  const float* W_user = (const float*)d_in[2];
  const float* b_user = (const float*)d_in[3];
  const float* W_movie = (const float*)d_in[4];
  const float* b_movie = (const float*)d_in[5];
  const float* u2m1_Wl = (const float*)d_in[6];
  const float* u2m1_bl = (const float*)d_in[7];
  const float* u2m1_Wr = (const float*)d_in[8];
  const float* m2u1_Wl = (const float*)d_in[9];
  const float* m2u1_bl = (const float*)d_in[10];
  const float* m2u1_Wr = (const float*)d_in[11];
  const float* u2m2_Wl = (const float*)d_in[12];
  const float* u2m2_bl = (const float*)d_in[13];
  const float* u2m2_Wr = (const float*)d_in[14];
  const float* m2u2_Wl = (const float*)d_in[15];
  const float* m2u2_bl = (const float*)d_in[16];
  const float* m2u2_Wr = (const float*)d_in[17];
  const float* u2u_Wl = (const float*)d_in[18];
  const float* u2u_bl = (const float*)d_in[19];
  const float* u2u_Wr = (const float*)d_in[20];
  const float* p1_W = (const float*)d_in[21];
  const float* p1_b = (const float*)d_in[22];
  const float* bn_gamma = (const float*)d_in[23];
  const float* bn_beta = (const float*)d_in[24];
  const float* bn_mean = (const float*)d_in[25];
  const float* bn_var = (const float*)d_in[26];
  const float* p2_W = (const float*)d_in[27];
  const float* p2_b = (const float*)d_in[28];
  const int* rated_src = (const int*)d_in[29];
  const int* rated_dst = (const int*)d_in[30];
  const int* uu_src = (const int*)d_in[31];
  const int* uu_dst = (const int*)d_in[32];

  // ---- workspace layout (~110.5 MB; known-good footprint is 113 MB) ----
  ushort_t* ux = (ushort_t*)d_ws;                       // NU*128 bf16
  ushort_t* mx = ux + (size_t)NUSR * DH;                // NM*128
  ushort_t* agg = mx + (size_t)NMOV * DH;               // NU*128 (pu; bkt_d/bkt_u alias pre-fill)
  ushort_t* pm = agg + (size_t)NUSR * DH;               // NM*128
  ushort_t* Wt = pm + (size_t)NMOV * DH;                // 6 * 32768
  ushort_t* WtU = Wt + 6 * 32768;                       // 128*64
  ushort_t* WtM = WtU + 8192;                           // 128*128
  float* SEP = (float*)(WtM + 16384);                   // 128
  float* TEP = SEP + DH;                                // 128
  int* col_m = (int*)(TEP + DH);                        // NMOV*CAPM ints
  ushort_t* col_u = (ushort_t*)(col_m + (size_t)NMOV * CAPM);   // NUSR*CAPU ushorts
  int* col_uu = (int*)(col_u + (size_t)NUSR * CAPU);    // NUSR*CAPUU ints
  int* cntbuf = col_uu + (size_t)NUSR * CAPUU;          // NMOV+2*NUSR+NBT
  uchar_t* ux8 = (uchar_t*)(cntbuf + (NMOV + 2 * NUSR + NBT));  // NU*128 fp8
  uchar_t* mx8 = ux8 + (size_t)NUSR * DH;               // NM*128 fp8
  uint2* bkt_s2 = (uint2*)(mx8 + (size_t)NMOV * DH);    // 128*BKS uint2 (8.65MB, survives to ep)
  int* cnt_m = cntbuf;
  int* cnt_u = cntbuf + NMOV;
  int* cnt_uu = cntbuf + NMOV + NUSR;
  int* bcnt = cntbuf + NMOV + 2 * NUSR;                 // NBT bucket cursors

  // d/u edge buckets alias agg (6.6MB < 25.6MB; both drained by csr_k which
  // runs before the first agg_mean4_k write to agg)
  unsigned* bkt_d = (unsigned*)agg;
  unsigned* bkt_u = bkt_d + (size_t)NBD * BKD;

  ushort_t* Wt_u2m1 = Wt + 0 * 32768;
  ushort_t* Wt_m2u1 = Wt + 1 * 32768;
  ushort_t* Wt_u2m2 = Wt + 2 * 32768;
  ushort_t* Wt_m2u2 = Wt + 3 * 32768;
  ushort_t* Wt_u2u  = Wt + 4 * 32768;
  ushort_t* Wt_p1   = Wt + 5 * 32768;
  ushort_t* pu = agg;  // alias: agg dead after last sage layer

  // ---- fused weight prep + BN params + bcnt zero ----
  PrepArgs pa;
  pa.Wl[0] = u2m1_Wl; pa.Wr[0] = u2m1_Wr;
  pa.Wl[1] = m2u1_Wl; pa.Wr[1] = m2u1_Wr;
  pa.Wl[2] = u2m2_Wl; pa.Wr[2] = u2m2_Wr;
  pa.Wl[3] = m2u2_Wl; pa.Wr[3] = m2u2_Wr;
  pa.Wl[4] = u2u_Wl;  pa.Wr[4] = u2u_Wr;
  pa.Wl[5] = p1_W;    pa.Wr[5] = p1_W + DH * DH;
  prep_all_k<<<865, 256, 0, stream>>>(
      pa, Wt, W_user, W_movie, WtU, WtM,
      p1_b, bn_gamma, bn_beta, bn_mean, bn_var, SEP, TEP, bcnt);

  // ---- two-phase fill (fine bins -> LDS CSR assembly), then input linears ----
  bin_rated_k<<<NBINB, 256, 0, stream>>>(
      rated_src, rated_dst, bkt_d, bkt_s2, bcnt);
  bin_uu_k<<<NBINB, 256, 0, stream>>>(uu_src, uu_dst, bkt_u, bcnt);
  csr_k<<<NBT, 256, 0, stream>>>(
      bkt_d, bkt_s2, bkt_u, bcnt, cnt_m, cnt_u, cnt_uu, col_m, col_u, col_uu);
  lin2_k<<<GLU + GLM, 256, 0, stream>>>(
      user_feat, WtU, b_user, ux, ux8, movie_feat, WtM, b_movie, mx, mx8);

  // ---- 5 SAGE layers (fp8 gather + LDS-staged-Wt MFMA) ----
  const int gaM = (NMOV + 15) / 16, gaU = (NUSR + 15) / 16;
  // u2m1: gather ux8 -> agg; update mx (+mx8, needed by m2u1 agg)
  agg_mean4_k<int, CAPM, 16><<<gaM, 256, 0, stream>>>(ux8, cnt_m, col_m, agg, NMOV);
  sage_mfma_k<<<GSM, 256, 0, stream>>>(agg, mx, Wt_u2m1, u2m1_bl, mx, mx8, NMOV);
  // m2u1: gather mx8 -> agg; update ux (+ux8, needed by u2m2 agg)
  agg_mean4_k<ushort_t, CAPU, 8><<<gaU, 256, 0, stream>>>(mx8, cnt_u, col_u, agg, NUSR);
  sage_mfma_k<<<GSU, 256, 0, stream>>>(agg, ux, Wt_m2u1, m2u1_bl, ux, ux8, NUSR);
  // u2m2
  agg_mean4_k<int, CAPM, 16><<<gaM, 256, 0, stream>>>(ux8, cnt_m, col_m, agg, NMOV);
  sage_mfma_k<<<GSM, 256, 0, stream>>>(agg, mx, Wt_u2m2, u2m2_bl, mx, mx8, NMOV);
  // m2u2
  agg_mean4_k<ushort_t, CAPU, 8><<<gaU, 256, 0, stream>>>(mx8, cnt_u, col_u, agg, NUSR);
  sage_mfma_k<<<GSU, 256, 0, stream>>>(agg, ux, Wt_m2u2, m2u2_bl, ux, ux8, NUSR);
  // u2u: final user layer; fp8 copy no longer needed afterwards
  agg_mean4_k<int, CAPUU, 8><<<gaU, 256, 0, stream>>>(ux8, cnt_uu, col_uu, agg, NUSR);
  sage_mfma_k<<<GSU, 256, 0, stream>>>(agg, ux, Wt_u2u, u2u_bl, ux, (uchar_t*)nullptr, NUSR);

  // ---- factored edge MLP (S folded into Wt_p1, T into pm bias) ----
  const int gmU = (NUSR + 127) / 128, gmM = (NMOV + 127) / 128;
  proj2_k<<<gmU + gmM, 256, 0, stream>>>(ux, mx, Wt_p1, TEP, pu, pm, gmU);
  ep_bkt_k<<<NEPB, 256, 0, stream>>>(
      pu, pm, bkt_s2, bcnt, p2_W, p2_b, (float*)d_out);
}